// Round 5
// baseline (695.194 us; speedup 1.0000x reference)
//
#include <hip/hip_runtime.h>
#include <hip/hip_bf16.h>
#include <cmath>

#define B_ 4
#define S_ 2048
#define D_ 1024
#define H_ 16
#define DH_ 64

typedef __attribute__((ext_vector_type(8))) short short8;
typedef __attribute__((ext_vector_type(4))) float f32x4;
#define MFMA_BF16(a, b, c) __builtin_amdgcn_mfma_f32_16x16x32_bf16(a, b, c, 0, 0, 0)

static __device__ __forceinline__ float b2f(unsigned short u) {
  union { unsigned int i; float f; } x; x.i = ((unsigned int)u) << 16; return x.f;
}
static __device__ __forceinline__ unsigned short f2b(float f) {
  union { float f; unsigned int i; } x; x.f = f;
  unsigned int r = x.i + 0x7FFFu + ((x.i >> 16) & 1u);
  return (unsigned short)(r >> 16);
}
// packed 2x f32 -> 2x bf16 (RNE), low = a
static __device__ __forceinline__ unsigned int pk2(float a, float b) {
  __hip_bfloat162 h = __float22bfloat162_rn(make_float2(a, b));
  return *(unsigned int*)&h;
}
// exact x mod 96 for 0 <= x < ~1e6
static __device__ __forceinline__ int mod96(int x) {
  int t = x >> 5;
  int q = (t * 43691) >> 17;  // floor(t/3), exact for t < 32768
  int m3 = t - q * 3;
  return (x & 31) + (m3 << 5);
}
static __device__ __forceinline__ int clampS(int x) {
  return x < 0 ? 0 : (x > S_ - 1 ? S_ - 1 : x);
}
// async global->LDS, 16B per lane; lds dest must be wave-uniform base (+lane*16)
typedef __attribute__((address_space(3))) unsigned int lds_u32_t;
typedef __attribute__((address_space(1))) const unsigned int glb_u32_t;
static __device__ __forceinline__ void gload_lds16(const void* g, void* l) {
  __builtin_amdgcn_global_load_lds((glb_u32_t*)g, (lds_u32_t*)l, 16, 0, 0);
}

// ---------------- fused prep: ln | cast | pe | wtrans x5 ----------------
// grid 1D: [0,8192) ln rows; [8192,16384) cast; [16384,20480) pe; [20480,21760) wtrans
__global__ __launch_bounds__(256) void prep_kernel(
    const float* __restrict__ inputs, const float* __restrict__ gamma,
    const float* __restrict__ beta, unsigned short* __restrict__ xb,
    const float* __restrict__ pre, unsigned short* __restrict__ preb,
    const double* __restrict__ dt, unsigned short* __restrict__ pe,
    const float* __restrict__ Wq, unsigned short* __restrict__ wtq,
    const float* __restrict__ Wk, unsigned short* __restrict__ wtk,
    const float* __restrict__ Wv, unsigned short* __restrict__ wtv,
    const float* __restrict__ Wp, unsigned short* __restrict__ wtp,
    const float* __restrict__ Wo, unsigned short* __restrict__ wto) {
  __shared__ __align__(16) float shf[64 * 65];  // wtrans tile; ln aliases head
  int bid = blockIdx.x;
  int tid = threadIdx.x;
  if (bid < 8192) {
    // ---- LayerNorm -> bf16 ----
    int row = bid;
    float4 val = ((const float4*)(inputs + (size_t)row * D_))[tid];
    float s = val.x + val.y + val.z + val.w;
    float sq = val.x * val.x + val.y * val.y + val.z * val.z + val.w * val.w;
#pragma unroll
    for (int o = 32; o > 0; o >>= 1) {
      s += __shfl_down(s, o);
      sq += __shfl_down(sq, o);
    }
    int wid = tid >> 6;
    if ((tid & 63) == 0) { shf[wid] = s; shf[4 + wid] = sq; }
    __syncthreads();
    if (tid == 0) {
      float ts = shf[0] + shf[1] + shf[2] + shf[3];
      float tq = shf[4] + shf[5] + shf[6] + shf[7];
      float mu = ts * (1.0f / D_);
      float var = tq * (1.0f / D_) - mu * mu;
      shf[8] = mu;
      shf[9] = rsqrtf(var + 1e-5f);
    }
    __syncthreads();
    float mu = shf[8], rs = shf[9];
    float4 g = ((const float4*)gamma)[tid];
    float4 be = ((const float4*)beta)[tid];
    ushort4 o;
    o.x = f2b((val.x - mu) * rs * g.x + be.x);
    o.y = f2b((val.y - mu) * rs * g.y + be.y);
    o.z = f2b((val.z - mu) * rs * g.z + be.z);
    o.w = f2b((val.w - mu) * rs * g.w + be.w);
    *(ushort4*)(xb + (size_t)row * D_ + tid * 4) = o;
    return;
  }
  bid -= 8192;
  if (bid < 8192) {
    // ---- fp32 -> bf16 cast ----
    size_t idx = (size_t)(bid * 256 + tid) * 4;
    float4 v = *(const float4*)(pre + idx);
    ushort4 o; o.x = f2b(v.x); o.y = f2b(v.y); o.z = f2b(v.z); o.w = f2b(v.w);
    *(ushort4*)(preb + idx) = o;
    return;
  }
  bid -= 8192;
  if (bid < 4096) {
    // ---- sinusoidal PE -> bf16 (f64 table angle + f32 sincos) ----
    int idx = bid * 256 + tid;  // [0, S*D/2)
    int t = idx >> 9;
    int i = idx & 511;
    double ang = (double)t * dt[i];
    double k = floor(ang * 0.15915494309189535);
    float red = (float)(ang - k * 6.283185307179586);
    ushort2 sc;
    sc.x = f2b(sinf(red));
    sc.y = f2b(cosf(red));
    *(ushort2*)(pe + (size_t)t * D_ + 2 * i) = sc;
    return;
  }
  bid -= 4096;
  // ---- W[K,N] fp32 -> WT[N,K] bf16 (64x64 tiles) ----
  const float* W; unsigned short* WT;
  switch (bid >> 8) {
    case 0: W = Wq; WT = wtq; break;
    case 1: W = Wk; WT = wtk; break;
    case 2: W = Wv; WT = wtv; break;
    case 3: W = Wp; WT = wtp; break;
    default: W = Wo; WT = wto; break;
  }
  int tile = bid & 255;
  int n0 = (tile & 15) * 64, k0 = (tile >> 4) * 64;
#pragma unroll
  for (int c = 0; c < 4; c++) {
    int idx = tid + c * 256;
    int r = idx >> 4;
    int ch = (idx & 15) * 4;
    float4 d = *(const float4*)(W + (size_t)(k0 + r) * D_ + n0 + ch);
    shf[r * 65 + ch] = d.x; shf[r * 65 + ch + 1] = d.y;
    shf[r * 65 + ch + 2] = d.z; shf[r * 65 + ch + 3] = d.w;
  }
  __syncthreads();
  {
    int n = tid >> 2;
    int ch = (tid & 3) * 16;
    unsigned short tmp[8];
#pragma unroll
    for (int half = 0; half < 2; half++) {
#pragma unroll
      for (int e = 0; e < 8; e++) tmp[e] = f2b(shf[(ch + half * 8 + e) * 65 + n]);
      *(short8*)(WT + (size_t)(n0 + n) * D_ + k0 + ch + half * 8) = *(short8*)tmp;
    }
  }
}

// ---------------- bf16 MFMA GEMM: C[M,N] = A[M,K] @ BT[N,K]^T + bias ----------------
template <bool F32OUT>
__global__ __launch_bounds__(256) void gemm_bf16_t(const unsigned short* __restrict__ A,
                                                   const unsigned short* __restrict__ BT,
                                                   const float* __restrict__ bias,
                                                   void* __restrict__ Cv,
                                                   int M, int N, int K) {
  __shared__ __align__(16) unsigned short As[128 * 32];
  __shared__ __align__(16) unsigned short Bs[128 * 32];
  const int tid = threadIdx.x;
  const int wid = tid >> 6, lane = tid & 63, quad = lane >> 4, l15 = lane & 15;
  const int m0 = blockIdx.y * 128, n0 = blockIdx.x * 128;
  const int moff = (wid >> 1) * 64, noff = (wid & 1) * 64;
  f32x4 acc[4][4];
#pragma unroll
  for (int i = 0; i < 4; i++)
#pragma unroll
    for (int j = 0; j < 4; j++) acc[i][j] = (f32x4){0.f, 0.f, 0.f, 0.f};

  const int cb0 = wid * 64;
  const int c0 = cb0 + lane;
  const int r0 = c0 >> 2, ch0 = (c0 & 3) * 8;
  const int c1 = c0 + 256;
  const int r1 = c1 >> 2, ch1 = (c1 & 3) * 8;

  for (int k0 = 0; k0 < K; k0 += 32) {
    __syncthreads();
    gload_lds16(A + (size_t)(m0 + r0) * K + k0 + ch0, &As[cb0 * 8]);
    gload_lds16(BT + (size_t)(n0 + r0) * K + k0 + ch0, &Bs[cb0 * 8]);
    gload_lds16(A + (size_t)(m0 + r1) * K + k0 + ch1, &As[(cb0 + 256) * 8]);
    gload_lds16(BT + (size_t)(n0 + r1) * K + k0 + ch1, &Bs[(cb0 + 256) * 8]);
    __syncthreads();
    short8 af[4], bf[4];
#pragma unroll
    for (int i = 0; i < 4; i++)
      af[i] = *(const short8*)&As[(moff + i * 16 + l15) * 32 + quad * 8];
#pragma unroll
    for (int j = 0; j < 4; j++)
      bf[j] = *(const short8*)&Bs[(noff + j * 16 + l15) * 32 + quad * 8];
#pragma unroll
    for (int i = 0; i < 4; i++)
#pragma unroll
      for (int j = 0; j < 4; j++) acc[i][j] = MFMA_BF16(af[i], bf[j], acc[i][j]);
  }
#pragma unroll
  for (int i = 0; i < 4; i++) {
    int row = m0 + moff + i * 16 + quad * 4;
#pragma unroll
    for (int j = 0; j < 4; j++) {
      int col = n0 + noff + j * 16 + l15;
      float bb = bias ? bias[col] : 0.f;
#pragma unroll
      for (int g = 0; g < 4; g++) {
        if (F32OUT)
          ((float*)Cv)[(size_t)(row + g) * N + col] = acc[i][j][g] + bb;
        else
          ((unsigned short*)Cv)[(size_t)(row + g) * N + col] = f2b(acc[i][j][g] + bb);
      }
    }
  }
}

// ---------------- fused Q+K GEMM: BT = [wtq ; wtk] (2048 rows), N=2048 ----------------
__global__ __launch_bounds__(256) void gemm_qk_bf16(const unsigned short* __restrict__ A,
                                                    const unsigned short* __restrict__ BT,
                                                    const float* __restrict__ bq,
                                                    const float* __restrict__ bk,
                                                    unsigned short* __restrict__ outQ,
                                                    unsigned short* __restrict__ outK) {
  const int K = D_;
  __shared__ __align__(16) unsigned short As[128 * 32];
  __shared__ __align__(16) unsigned short Bs[128 * 32];
  const int tid = threadIdx.x;
  const int wid = tid >> 6, lane = tid & 63, quad = lane >> 4, l15 = lane & 15;
  const int m0 = blockIdx.y * 128, n0 = blockIdx.x * 128;
  const int moff = (wid >> 1) * 64, noff = (wid & 1) * 64;
  f32x4 acc[4][4];
#pragma unroll
  for (int i = 0; i < 4; i++)
#pragma unroll
    for (int j = 0; j < 4; j++) acc[i][j] = (f32x4){0.f, 0.f, 0.f, 0.f};

  const int cb0 = wid * 64;
  const int c0 = cb0 + lane;
  const int r0 = c0 >> 2, ch0 = (c0 & 3) * 8;
  const int c1 = c0 + 256;
  const int r1 = c1 >> 2, ch1 = (c1 & 3) * 8;

  for (int k0 = 0; k0 < K; k0 += 32) {
    __syncthreads();
    gload_lds16(A + (size_t)(m0 + r0) * K + k0 + ch0, &As[cb0 * 8]);
    gload_lds16(BT + (size_t)(n0 + r0) * K + k0 + ch0, &Bs[cb0 * 8]);
    gload_lds16(A + (size_t)(m0 + r1) * K + k0 + ch1, &As[(cb0 + 256) * 8]);
    gload_lds16(BT + (size_t)(n0 + r1) * K + k0 + ch1, &Bs[(cb0 + 256) * 8]);
    __syncthreads();
    short8 af[4], bf[4];
#pragma unroll
    for (int i = 0; i < 4; i++)
      af[i] = *(const short8*)&As[(moff + i * 16 + l15) * 32 + quad * 8];
#pragma unroll
    for (int j = 0; j < 4; j++)
      bf[j] = *(const short8*)&Bs[(noff + j * 16 + l15) * 32 + quad * 8];
#pragma unroll
    for (int i = 0; i < 4; i++)
#pragma unroll
      for (int j = 0; j < 4; j++) acc[i][j] = MFMA_BF16(af[i], bf[j], acc[i][j]);
  }
  const float* bias = (n0 < D_) ? bq : bk;
  unsigned short* outp = (n0 < D_) ? outQ : outK;
  const int nn0 = n0 & (D_ - 1);
#pragma unroll
  for (int i = 0; i < 4; i++) {
    int row = m0 + moff + i * 16 + quad * 4;
#pragma unroll
    for (int j = 0; j < 4; j++) {
      int col = nn0 + noff + j * 16 + l15;
      float bb = bias[col];
#pragma unroll
      for (int g = 0; g < 4; g++)
        outp[(size_t)(row + g) * D_ + col] = f2b(acc[i][j][g] + bb);
    }
  }
}

// ---------------- fused post: vtrans | cw ----------------
// grid 1D: [0,2048) vtrans tiles; [2048,2176) cw
__global__ __launch_bounds__(256) void post_kernel(const unsigned short* __restrict__ v,
                                                   unsigned short* __restrict__ vt,
                                                   const unsigned short* __restrict__ p,
                                                   const float* __restrict__ ub,
                                                   const float* __restrict__ vbb,
                                                   float* __restrict__ cw) {
  __shared__ __align__(16) unsigned short t[64 * 72];
  int bid = blockIdx.x;
  int tid = threadIdx.x;
  if (bid < 2048) {
    int s0 = (bid & 31) * 64, h = (bid >> 5) & 15, b = bid >> 9;
#pragma unroll
    for (int c = 0; c < 2; c++) {
      int idx = tid + c * 256;
      int r = idx >> 3, ch = (idx & 7) * 8;
      short8 d = *(const short8*)(v + (((size_t)b * S_ + s0 + r) * H_ + h) * DH_ + ch);
      *(short8*)&t[r * 72 + ch] = d;
    }
    __syncthreads();
    int dh = tid >> 2, ch = tid & 3;
    unsigned short tmp[8];
#pragma unroll
    for (int half = 0; half < 2; half++) {
#pragma unroll
      for (int e = 0; e < 8; e++) tmp[e] = t[(ch * 16 + half * 8 + e) * 72 + dh];
      *(short8*)(vt + ((size_t)(b * H_ + h) * 64 + dh) * S_ + s0 + ch * 16 + half * 8) =
          *(short8*)tmp;
    }
    return;
  }
  int idx = (bid - 2048) * 256 + tid;  // [0, H*S)
  int r = idx & (S_ - 1), h = idx >> 11;
  float s = 0.f;
#pragma unroll 8
  for (int c = 0; c < 64; c++)
    s += (vbb[h * 64 + c] - ub[h * 64 + c]) * b2f(p[(size_t)r * D_ + h * 64 + c]);
  cw[idx] = s;
}

// ---------------- MFMA flash attention with rel-shift (transposed score) -------
// R5: V tile no longer LDS-staged -- PV fragments are contiguous 16B runs of vtg
// (row dh, col j), loaded direct to registers with 1-jt-deep prefetch (issued
// after PV, consumed a full loop body later). LDS 45056 -> 39936 B -> 4 blocks/CU.
__global__ __launch_bounds__(256) void attn_kernel(const unsigned short* __restrict__ q,
                                                   const unsigned short* __restrict__ kg,
                                                   const unsigned short* __restrict__ vtg,
                                                   const unsigned short* __restrict__ pg,
                                                   const float* __restrict__ ub,
                                                   const float* __restrict__ cw,
                                                   unsigned short* __restrict__ ctx) {
  // XCD-bijective swizzle (nwg = 2048 = 8*256)
  int flat = blockIdx.x + 32 * (blockIdx.y + 16 * blockIdx.z);
  int swz = (flat & 7) * 256 + (flat >> 3);
  const int i0 = (swz & 31) * 64;
  const int h = (swz >> 5) & 15;
  const int b = swz >> 9;
  const int tid = threadIdx.x;
  const int wid = tid >> 6, lane = tid & 63, quad = lane >> 4, l15 = lane & 15;
  const int wr0 = wid * 16;
  const int ib = i0 >> 5;  // first mixed jt

  __shared__ __align__(16) unsigned short ks[32 * 72];     // K tile [j][dh]
  __shared__ __align__(16) unsigned short ps[32 * 72];     // staged p rows [n][dh]
  __shared__ __align__(16) unsigned short prb[64 * 40];    // probs [i][j] (also prologue scratch)
  __shared__ __align__(16) unsigned short bandA[64 * 100]; // ring (q_i+v).p[r], col mod96(r+1)
  __shared__ __align__(16) unsigned short bandB[64 * 100]; // ring (q_{i+1}+v).p[r], col mod96(r+2)

  const int srow = tid >> 3, sch = (tid & 7) * 8;  // 32x64 staging (K, p)

  const unsigned short* kgp = kg + ((size_t)b * S_ * H_ + h) * DH_ + (size_t)srow * H_ * DH_ + sch;
  // per-thread V fragment base: row dh = l15 (+ct*16), col j0 + quad*8
  const unsigned short* vdir = vtg + ((size_t)(b * H_ + h) * 64 + l15) * S_ + quad * 8;
  const unsigned short* pgp = pg + h * 64 + sch;
  const float* cwh = cw + h * S_;

  // ---- direct q + u_bias fragment loads (one-time) ----
  short8 qa00, qa01, qa10, qa11;
  {
    auto ldq = [&](int r, int c0) -> short8 {
      int qi = i0 + r; if (qi > S_ - 1) qi = S_ - 1;
      short8 raw = *(const short8*)(q + (((size_t)b * S_ + qi) * H_ + h) * DH_ + c0);
      unsigned short t[8];
#pragma unroll
      for (int e = 0; e < 8; e++)
        t[e] = f2b(b2f((unsigned short)raw[e]) + ub[h * 64 + c0 + e]);
      return *(short8*)t;
    };
    qa00 = ldq(wr0 + l15, quad * 8);
    qa01 = ldq(wr0 + l15, 32 + quad * 8);
    qa10 = ldq(wr0 + l15 + 1, quad * 8);
    qa11 = ldq(wr0 + l15 + 1, 32 + quad * 8);
  }

  const int brow = (wr0 + l15) * 100;  // own band row (write AND read)

  // band MFMA, swapped operands: D[m=r-local][n=i]; thread -> 4 consecutive r, own i
  auto band_compute = [&](const unsigned short* src, int w, int rhi) {
    int rbase = rhi - 31;
    short8 a0 = w ? qa10 : qa00;
    short8 a1 = w ? qa11 : qa01;
    unsigned short* band = w ? bandB : bandA;
    const int OFF = w ? 2 : 1;
#pragma unroll
    for (int ct = 0; ct < 2; ct++) {
      short8 b0 = *(const short8*)&src[(ct * 16 + l15) * 72 + quad * 8];
      short8 b1 = *(const short8*)&src[(ct * 16 + l15) * 72 + 32 + quad * 8];
      f32x4 acc = (f32x4){0.f, 0.f, 0.f, 0.f};
      acc = MFMA_BF16(b0, a0, acc);   // A = p rows, B = q rows
      acc = MFMA_BF16(b1, a1, acc);
      int r0 = rbase + ct * 16 + quad * 4;
      float c0 = cwh[clampS(r0)];
      float c1 = cwh[clampS(r0 + 1)];
      float c2 = cwh[clampS(r0 + 2)];
      float c3 = cwh[clampS(r0 + 3)];
      int col = mod96(r0 + 960 + OFF);   // === 0 mod 4 -> b64 aligned
      uint2 pv = make_uint2(pk2(acc[0] + c0, acc[1] + c1), pk2(acc[2] + c2, acc[3] + c3));
      *(uint2*)&band[brow + col] = pv;
      if (col == 0) *(uint2*)&band[brow + 96] = pv;  // mirror guard 96..99
    }
  };

  // ---- prologue: 3 A backfills + 2 B backfills (ps + prb as scratch slots) ----
  {
    int TW[5] = {0, 0, 0, 1, 1};
    int TR[5] = {S_ + 30 - i0 - 64, S_ + 30 - i0 - 32, S_ + 30 - i0, 29, 61};
    for (int t0 = 0; t0 < 5; t0 += 2) {
      if (t0) __syncthreads();
      {
        int rr = TR[t0] - 31 + srow;
        int rc = clampS(rr);
        *(short8*)&ps[srow * 72 + sch] = *(const short8*)(pgp + (size_t)rc * D_);
      }
      if (t0 + 1 < 5) {
        int rr = TR[t0 + 1] - 31 + srow;
        int rc = clampS(rr);
        *(short8*)&prb[srow * 72 + sch] = *(const short8*)(pgp + (size_t)rc * D_);
      }
      if (t0 == 0) {
        *(short8*)&ks[srow * 72 + sch] = *(const short8*)kgp;
      }
      __syncthreads();
      band_compute(ps, TW[t0], TR[t0]);
      if (t0 + 1 < 5) band_compute(prb, TW[t0 + 1], TR[t0 + 1]);
    }
    __syncthreads();
  }

  float lsum = 0.f;  // per thread: i = i0 + wr0 + l15 fixed
  f32x4 Oa[4];
#pragma unroll
  for (int ct = 0; ct < 4; ct++) Oa[ct] = (f32x4){0.f, 0.f, 0.f, 0.f};

  // ring cols for (g=0, ct=0), advance +32 mod 96 / jt; include OFF rotation
  int cA = mod96(S_ + quad * 4 - i0 - wr0 - l15);          // OFF_A=1 folded in
  int cB = mod96(2112 + quad * 4 - i0 - wr0 - l15);        // OFF_B=2 folded in
  int cwin = 0, crhi = 0, chave = 0;

  const float SCL = 0.03125f;
  const unsigned int prbw = (wr0 + l15) * 40 + quad * 4;

  // ---- preload V fragments for jt=0 (direct from global) ----
  short8 vf0, vf1, vf2, vf3;
  vf0 = *(const short8*)(vdir);
  vf1 = *(const short8*)(vdir + 16 * (size_t)S_);
  vf2 = *(const short8*)(vdir + 32 * (size_t)S_);
  vf3 = *(const short8*)(vdir + 48 * (size_t)S_);

  for (int jt = 0; jt < 64; jt++) {
    const int j0 = jt * 32;
    // ---- prefetch K/p tile jt+1 into registers ----
    short8 pf_k, pf_p;
    int pwin = 0, prhi = 0, havep = 0;
    {
      int j0n = (jt < 63) ? j0 + 32 : j0;
      pf_k = *(const short8*)(kgp + (size_t)j0n * (H_ * DH_));
      int j0x = j0 + 32;
      if (j0x <= i0 + 63) { pwin = 0; prhi = S_ + 30 - i0 + j0x; havep = 1; }
      else if (jt < 63)   { pwin = 1; prhi = j0x - i0 + 29;      havep = 1; }
      if (havep) {
        int rr = prhi - 31 + srow;
        int rc = clampS(rr);
        pf_p = *(const short8*)(pgp + (size_t)rc * D_);
      }
    }
    // ---- band MFMA for the task staged at jt-1 ----
    if (chave) band_compute(ps, cwin, crhi);
    // ---- content MFMA, transposed: Sc^T rows=j, cols=i ----
    f32x4 cc[2];
    {
#pragma unroll
      for (int ct = 0; ct < 2; ct++) {
        short8 a0 = *(const short8*)&ks[(ct * 16 + l15) * 72 + quad * 8];
        short8 a1 = *(const short8*)&ks[(ct * 16 + l15) * 72 + 32 + quad * 8];
        f32x4 acc = (f32x4){0.f, 0.f, 0.f, 0.f};
        acc = MFMA_BF16(a0, qa00, acc);
        acc = MFMA_BF16(a1, qa01, acc);
        cc[ct] = acc;
      }
    }
    // ---- score: thread = (i fixed, j = j0 + ct*16 + quad*4 + g) ----
    if (jt < ib) {
#pragma unroll
      for (int ct = 0; ct < 2; ct++) {
        int c0 = ct ? (cA + 16 >= 96 ? cA + 16 - 96 : cA + 16) : cA;
        const unsigned short* base = &bandA[brow + c0];
        float e0 = __expf((cc[ct][0] + b2f(base[0])) * SCL);
        float e1 = __expf((cc[ct][1] + b2f(base[1])) * SCL);
        float e2 = __expf((cc[ct][2] + b2f(base[2])) * SCL);
        float e3 = __expf((cc[ct][3] + b2f(base[3])) * SCL);
        *(uint2*)&prb[prbw + ct * 16] = make_uint2(pk2(e0, e1), pk2(e2, e3));
        lsum += (e0 + e1) + (e2 + e3);
      }
    } else if (jt >= ib + 3) {
#pragma unroll
      for (int ct = 0; ct < 2; ct++) {
        int c0 = ct ? (cB + 16 >= 96 ? cB + 16 - 96 : cB + 16) : cB;
        const unsigned short* base = &bandB[brow + c0];
        float e0 = __expf((cc[ct][0] + b2f(base[0])) * SCL);
        float e1 = __expf((cc[ct][1] + b2f(base[1])) * SCL);
        float e2 = __expf((cc[ct][2] + b2f(base[2])) * SCL);
        float e3 = __expf((cc[ct][3] + b2f(base[3])) * SCL);
        *(uint2*)&prb[prbw + ct * 16] = make_uint2(pk2(e0, e1), pk2(e2, e3));
        lsum += (e0 + e1) + (e2 + e3);
      }
    } else {
      // mixed: generic per element; OFF rotation applied (A:+1, B:+2)
#pragma unroll
      for (int ct = 0; ct < 2; ct++) {
        int jbase = j0 + ct * 16 + quad * 4;
        float ev[4];
#pragma unroll
        for (int g = 0; g < 4; g++) {
          int d = jbase + g - (i0 + wr0 + l15);
          float t;
          if (d == 1) t = 0.f;
          else if (d <= 0) t = b2f(bandA[brow + mod96(S_ + d)]);      // r=S-1+d, +1
          else t = b2f(bandB[brow + mod96(d)]);                        // r=d-2, +2
          ev[g] = __expf((cc[ct][g] + t) * SCL);
          lsum += ev[g];
        }
        *(uint2*)&prb[prbw + ct * 16] = make_uint2(pk2(ev[0], ev[1]), pk2(ev[2], ev[3]));
      }
    }
    // ---- PV MFMA: O[i 16][dh 64] += P(16x32) @ V(32x64); V from registers ----
    {
      short8 af = *(const short8*)&prb[(wr0 + l15) * 40 + quad * 8];
      Oa[0] = MFMA_BF16(af, vf0, Oa[0]);
      Oa[1] = MFMA_BF16(af, vf1, Oa[1]);
      Oa[2] = MFMA_BF16(af, vf2, Oa[2]);
      Oa[3] = MFMA_BF16(af, vf3, Oa[3]);
    }
    // ---- prefetch V for jt+1 (consumed at next PV, full loop body away) ----
    if (jt < 63) {
      const unsigned short* vr = vdir + j0 + 32;
      vf0 = *(const short8*)(vr);
      vf1 = *(const short8*)(vr + 16 * (size_t)S_);
      vf2 = *(const short8*)(vr + 32 * (size_t)S_);
      vf3 = *(const short8*)(vr + 48 * (size_t)S_);
    }
    // ---- commit prefetched K/p tile jt+1 ----
    __syncthreads();
    *(short8*)&ks[srow * 72 + sch] = pf_k;
    if (havep) *(short8*)&ps[srow * 72 + sch] = pf_p;
    cwin = pwin; crhi = prhi; chave = havep;
    __syncthreads();
    cA += 32; if (cA >= 96) cA -= 96;
    cB += 32; if (cB >= 96) cB -= 96;
  }
  // ---- epilogue ----
  float ltot = lsum;
  ltot += __shfl_xor(ltot, 16);
  ltot += __shfl_xor(ltot, 32);
#pragma unroll
  for (int g = 0; g < 4; g++) {
    float lg = __shfl(ltot, quad * 4 + g);
    float inv = 1.f / lg;
    int i = i0 + wr0 + quad * 4 + g;
    unsigned short* dst = ctx + ((size_t)b * S_ + i) * D_ + h * 64;
#pragma unroll
    for (int ct = 0; ct < 4; ct++) dst[ct * 16 + l15] = f2b(Oa[ct][g] * inv);
  }
}

extern "C" void kernel_launch(void* const* d_in, const int* in_sizes, int n_in,
                              void* d_out, int out_size, void* d_ws, size_t ws_size,
                              hipStream_t stream) {
  const float* inputs = (const float*)d_in[0];
  const float* pre_block = (const float*)d_in[1];
  const float* ln_gamma = (const float*)d_in[2];
  const float* ln_beta = (const float*)d_in[3];
  const float* Wq = (const float*)d_in[4];
  const float* bq = (const float*)d_in[5];
  const float* Wk = (const float*)d_in[6];
  const float* bk = (const float*)d_in[7];
  const float* Wv = (const float*)d_in[8];
  const float* bv = (const float*)d_in[9];
  const float* Wpos = (const float*)d_in[10];
  const float* u_bias = (const float*)d_in[11];
  const float* v_bias = (const float*)d_in[12];
  const float* Wo = (const float*)d_in[13];
  const float* bo = (const float*)d_in[14];
  float* out = (float*)d_out;

  char* ws = (char*)d_ws;
  const size_t NBS = (size_t)B_ * S_ * D_;  // 8388608
  unsigned short* xb = (unsigned short*)ws;
  unsigned short* ctx = (unsigned short*)ws;               // alias (xb dead after qk-GEMM)
  unsigned short* preb = (unsigned short*)(ws + NBS * 2);
  unsigned short* peb = (unsigned short*)(ws + NBS * 4);
  char* base = ws + NBS * 4 + (size_t)S_ * D_ * 2;
  unsigned short* wtq = (unsigned short*)(base);           // wtq||wtk contiguous (fused QK)
  unsigned short* wtk = (unsigned short*)(base + (size_t)D_ * D_ * 2);
  unsigned short* wtv = (unsigned short*)(base + (size_t)D_ * D_ * 4);
  unsigned short* wtp = (unsigned short*)(base + (size_t)D_ * D_ * 6);
  unsigned short* wto = (unsigned short*)(base + (size_t)D_ * D_ * 8);
  unsigned short* qb = (unsigned short*)(base + (size_t)D_ * D_ * 10);
  unsigned short* kb = qb + NBS;
  unsigned short* vb = kb + NBS;
  unsigned short* vtb = vb + NBS;
  unsigned short* pb = vtb + NBS;
  float* cww = (float*)(pb + (size_t)S_ * D_);
  double* divtab = (double*)(cww + (size_t)H_ * S_);  // dedicated 4KB slot

  // host-computed f64 div table (512 exps once; async H2D, graph-capture safe)
  static double h_divtab[512];
  static bool h_init = false;
  if (!h_init) {
    for (int i = 0; i < 512; i++)
      h_divtab[i] = exp(-(log(10000.0) * (2.0 * i) / (double)D_));
    h_init = true;
  }
  hipMemcpyAsync(divtab, h_divtab, 512 * sizeof(double), hipMemcpyHostToDevice, stream);

  prep_kernel<<<21760, 256, 0, stream>>>(inputs, ln_gamma, ln_beta, xb,
                                         pre_block, preb, divtab, peb,
                                         Wq, wtq, Wk, wtk, Wv, wtv, Wpos, wtp, Wo, wto);
  gemm_qk_bf16<<<dim3(16, 64), 256, 0, stream>>>(xb, wtq, bq, bk, qb, kb);
  gemm_bf16_t<false><<<dim3(8, 64), 256, 0, stream>>>(preb, wtv, bv, vb, B_ * S_, D_, D_);
  gemm_bf16_t<false><<<dim3(8, 16), 256, 0, stream>>>(peb, wtp, nullptr, pb, S_, D_, D_);
  post_kernel<<<2176, 256, 0, stream>>>(vb, vtb, pb, u_bias, v_bias, cww);
  attn_kernel<<<dim3(32, 16, 4), 256, 0, stream>>>(qb, kb, vtb, pb, u_bias, cww, ctx);
  gemm_bf16_t<true><<<dim3(8, 64), 256, 0, stream>>>(ctx, wto, bo, out, B_ * S_, D_, D_);
}

// Round 6
// 635.092 us; speedup vs baseline: 1.0946x; 1.0946x over previous
//
#include <hip/hip_runtime.h>
#include <hip/hip_bf16.h>
#include <cmath>

#define B_ 4
#define S_ 2048
#define D_ 1024
#define H_ 16
#define DH_ 64

typedef __attribute__((ext_vector_type(8))) short short8;
typedef __attribute__((ext_vector_type(4))) float f32x4;
#define MFMA_BF16(a, b, c) __builtin_amdgcn_mfma_f32_16x16x32_bf16(a, b, c, 0, 0, 0)

static __device__ __forceinline__ float b2f(unsigned short u) {
  union { unsigned int i; float f; } x; x.i = ((unsigned int)u) << 16; return x.f;
}
static __device__ __forceinline__ unsigned short f2b(float f) {
  union { float f; unsigned int i; } x; x.f = f;
  unsigned int r = x.i + 0x7FFFu + ((x.i >> 16) & 1u);
  return (unsigned short)(r >> 16);
}
// packed 2x f32 -> 2x bf16 (RNE), low = a
static __device__ __forceinline__ unsigned int pk2(float a, float b) {
  __hip_bfloat162 h = __float22bfloat162_rn(make_float2(a, b));
  return *(unsigned int*)&h;
}
// exact x mod 96 for 0 <= x < ~1e6
static __device__ __forceinline__ int mod96(int x) {
  int t = x >> 5;
  int q = (t * 43691) >> 17;  // floor(t/3), exact for t < 32768
  int m3 = t - q * 3;
  return (x & 31) + (m3 << 5);
}
static __device__ __forceinline__ int clampS(int x) {
  return x < 0 ? 0 : (x > S_ - 1 ? S_ - 1 : x);
}
// async global->LDS, 16B per lane; lds dest must be wave-uniform base (+lane*16)
typedef __attribute__((address_space(3))) unsigned int lds_u32_t;
typedef __attribute__((address_space(1))) const unsigned int glb_u32_t;
static __device__ __forceinline__ void gload_lds16(const void* g, void* l) {
  __builtin_amdgcn_global_load_lds((glb_u32_t*)g, (lds_u32_t*)l, 16, 0, 0);
}

// ---------------- fused prep: ln | cast | pe | wtrans x5 ----------------
// grid 1D: [0,8192) ln rows; [8192,16384) cast; [16384,20480) pe; [20480,21760) wtrans
__global__ __launch_bounds__(256) void prep_kernel(
    const float* __restrict__ inputs, const float* __restrict__ gamma,
    const float* __restrict__ beta, unsigned short* __restrict__ xb,
    const float* __restrict__ pre, unsigned short* __restrict__ preb,
    const double* __restrict__ dt, unsigned short* __restrict__ pe,
    const float* __restrict__ Wq, unsigned short* __restrict__ wtq,
    const float* __restrict__ Wk, unsigned short* __restrict__ wtk,
    const float* __restrict__ Wv, unsigned short* __restrict__ wtv,
    const float* __restrict__ Wp, unsigned short* __restrict__ wtp,
    const float* __restrict__ Wo, unsigned short* __restrict__ wto) {
  __shared__ __align__(16) float shf[64 * 65];  // wtrans tile; ln aliases head
  int bid = blockIdx.x;
  int tid = threadIdx.x;
  if (bid < 8192) {
    // ---- LayerNorm -> bf16 ----
    int row = bid;
    float4 val = ((const float4*)(inputs + (size_t)row * D_))[tid];
    float s = val.x + val.y + val.z + val.w;
    float sq = val.x * val.x + val.y * val.y + val.z * val.z + val.w * val.w;
#pragma unroll
    for (int o = 32; o > 0; o >>= 1) {
      s += __shfl_down(s, o);
      sq += __shfl_down(sq, o);
    }
    int wid = tid >> 6;
    if ((tid & 63) == 0) { shf[wid] = s; shf[4 + wid] = sq; }
    __syncthreads();
    if (tid == 0) {
      float ts = shf[0] + shf[1] + shf[2] + shf[3];
      float tq = shf[4] + shf[5] + shf[6] + shf[7];
      float mu = ts * (1.0f / D_);
      float var = tq * (1.0f / D_) - mu * mu;
      shf[8] = mu;
      shf[9] = rsqrtf(var + 1e-5f);
    }
    __syncthreads();
    float mu = shf[8], rs = shf[9];
    float4 g = ((const float4*)gamma)[tid];
    float4 be = ((const float4*)beta)[tid];
    ushort4 o;
    o.x = f2b((val.x - mu) * rs * g.x + be.x);
    o.y = f2b((val.y - mu) * rs * g.y + be.y);
    o.z = f2b((val.z - mu) * rs * g.z + be.z);
    o.w = f2b((val.w - mu) * rs * g.w + be.w);
    *(ushort4*)(xb + (size_t)row * D_ + tid * 4) = o;
    return;
  }
  bid -= 8192;
  if (bid < 8192) {
    // ---- fp32 -> bf16 cast ----
    size_t idx = (size_t)(bid * 256 + tid) * 4;
    float4 v = *(const float4*)(pre + idx);
    ushort4 o; o.x = f2b(v.x); o.y = f2b(v.y); o.z = f2b(v.z); o.w = f2b(v.w);
    *(ushort4*)(preb + idx) = o;
    return;
  }
  bid -= 8192;
  if (bid < 4096) {
    // ---- sinusoidal PE -> bf16 (f64 table angle + f32 sincos) ----
    int idx = bid * 256 + tid;  // [0, S*D/2)
    int t = idx >> 9;
    int i = idx & 511;
    double ang = (double)t * dt[i];
    double k = floor(ang * 0.15915494309189535);
    float red = (float)(ang - k * 6.283185307179586);
    ushort2 sc;
    sc.x = f2b(sinf(red));
    sc.y = f2b(cosf(red));
    *(ushort2*)(pe + (size_t)t * D_ + 2 * i) = sc;
    return;
  }
  bid -= 4096;
  // ---- W[K,N] fp32 -> WT[N,K] bf16 (64x64 tiles) ----
  const float* W; unsigned short* WT;
  switch (bid >> 8) {
    case 0: W = Wq; WT = wtq; break;
    case 1: W = Wk; WT = wtk; break;
    case 2: W = Wv; WT = wtv; break;
    case 3: W = Wp; WT = wtp; break;
    default: W = Wo; WT = wto; break;
  }
  int tile = bid & 255;
  int n0 = (tile & 15) * 64, k0 = (tile >> 4) * 64;
#pragma unroll
  for (int c = 0; c < 4; c++) {
    int idx = tid + c * 256;
    int r = idx >> 4;
    int ch = (idx & 15) * 4;
    float4 d = *(const float4*)(W + (size_t)(k0 + r) * D_ + n0 + ch);
    shf[r * 65 + ch] = d.x; shf[r * 65 + ch + 1] = d.y;
    shf[r * 65 + ch + 2] = d.z; shf[r * 65 + ch + 3] = d.w;
  }
  __syncthreads();
  {
    int n = tid >> 2;
    int ch = (tid & 3) * 16;
    unsigned short tmp[8];
#pragma unroll
    for (int half = 0; half < 2; half++) {
#pragma unroll
      for (int e = 0; e < 8; e++) tmp[e] = f2b(shf[(ch + half * 8 + e) * 65 + n]);
      *(short8*)(WT + (size_t)(n0 + n) * D_ + k0 + ch + half * 8) = *(short8*)tmp;
    }
  }
}

// ---------------- bf16 MFMA GEMM: C[M,N] = A[M,K] @ BT[N,K]^T + bias ----------------
template <bool F32OUT>
__global__ __launch_bounds__(256) void gemm_bf16_t(const unsigned short* __restrict__ A,
                                                   const unsigned short* __restrict__ BT,
                                                   const float* __restrict__ bias,
                                                   void* __restrict__ Cv,
                                                   int M, int N, int K) {
  __shared__ __align__(16) unsigned short As[128 * 32];
  __shared__ __align__(16) unsigned short Bs[128 * 32];
  const int tid = threadIdx.x;
  const int wid = tid >> 6, lane = tid & 63, quad = lane >> 4, l15 = lane & 15;
  const int m0 = blockIdx.y * 128, n0 = blockIdx.x * 128;
  const int moff = (wid >> 1) * 64, noff = (wid & 1) * 64;
  f32x4 acc[4][4];
#pragma unroll
  for (int i = 0; i < 4; i++)
#pragma unroll
    for (int j = 0; j < 4; j++) acc[i][j] = (f32x4){0.f, 0.f, 0.f, 0.f};

  const int cb0 = wid * 64;
  const int c0 = cb0 + lane;
  const int r0 = c0 >> 2, ch0 = (c0 & 3) * 8;
  const int c1 = c0 + 256;
  const int r1 = c1 >> 2, ch1 = (c1 & 3) * 8;

  for (int k0 = 0; k0 < K; k0 += 32) {
    __syncthreads();
    gload_lds16(A + (size_t)(m0 + r0) * K + k0 + ch0, &As[cb0 * 8]);
    gload_lds16(BT + (size_t)(n0 + r0) * K + k0 + ch0, &Bs[cb0 * 8]);
    gload_lds16(A + (size_t)(m0 + r1) * K + k0 + ch1, &As[(cb0 + 256) * 8]);
    gload_lds16(BT + (size_t)(n0 + r1) * K + k0 + ch1, &Bs[(cb0 + 256) * 8]);
    __syncthreads();
    short8 af[4], bf[4];
#pragma unroll
    for (int i = 0; i < 4; i++)
      af[i] = *(const short8*)&As[(moff + i * 16 + l15) * 32 + quad * 8];
#pragma unroll
    for (int j = 0; j < 4; j++)
      bf[j] = *(const short8*)&Bs[(noff + j * 16 + l15) * 32 + quad * 8];
#pragma unroll
    for (int i = 0; i < 4; i++)
#pragma unroll
      for (int j = 0; j < 4; j++) acc[i][j] = MFMA_BF16(af[i], bf[j], acc[i][j]);
  }
#pragma unroll
  for (int i = 0; i < 4; i++) {
    int row = m0 + moff + i * 16 + quad * 4;
#pragma unroll
    for (int j = 0; j < 4; j++) {
      int col = n0 + noff + j * 16 + l15;
      float bb = bias ? bias[col] : 0.f;
#pragma unroll
      for (int g = 0; g < 4; g++) {
        if (F32OUT)
          ((float*)Cv)[(size_t)(row + g) * N + col] = acc[i][j][g] + bb;
        else
          ((unsigned short*)Cv)[(size_t)(row + g) * N + col] = f2b(acc[i][j][g] + bb);
      }
    }
  }
}

// ---------------- fused Q+K GEMM: BT = [wtq ; wtk] (2048 rows), N=2048 ----------------
__global__ __launch_bounds__(256) void gemm_qk_bf16(const unsigned short* __restrict__ A,
                                                    const unsigned short* __restrict__ BT,
                                                    const float* __restrict__ bq,
                                                    const float* __restrict__ bk,
                                                    unsigned short* __restrict__ outQ,
                                                    unsigned short* __restrict__ outK) {
  const int K = D_;
  __shared__ __align__(16) unsigned short As[128 * 32];
  __shared__ __align__(16) unsigned short Bs[128 * 32];
  const int tid = threadIdx.x;
  const int wid = tid >> 6, lane = tid & 63, quad = lane >> 4, l15 = lane & 15;
  const int m0 = blockIdx.y * 128, n0 = blockIdx.x * 128;
  const int moff = (wid >> 1) * 64, noff = (wid & 1) * 64;
  f32x4 acc[4][4];
#pragma unroll
  for (int i = 0; i < 4; i++)
#pragma unroll
    for (int j = 0; j < 4; j++) acc[i][j] = (f32x4){0.f, 0.f, 0.f, 0.f};

  const int cb0 = wid * 64;
  const int c0 = cb0 + lane;
  const int r0 = c0 >> 2, ch0 = (c0 & 3) * 8;
  const int c1 = c0 + 256;
  const int r1 = c1 >> 2, ch1 = (c1 & 3) * 8;

  for (int k0 = 0; k0 < K; k0 += 32) {
    __syncthreads();
    gload_lds16(A + (size_t)(m0 + r0) * K + k0 + ch0, &As[cb0 * 8]);
    gload_lds16(BT + (size_t)(n0 + r0) * K + k0 + ch0, &Bs[cb0 * 8]);
    gload_lds16(A + (size_t)(m0 + r1) * K + k0 + ch1, &As[(cb0 + 256) * 8]);
    gload_lds16(BT + (size_t)(n0 + r1) * K + k0 + ch1, &Bs[(cb0 + 256) * 8]);
    __syncthreads();
    short8 af[4], bf[4];
#pragma unroll
    for (int i = 0; i < 4; i++)
      af[i] = *(const short8*)&As[(moff + i * 16 + l15) * 32 + quad * 8];
#pragma unroll
    for (int j = 0; j < 4; j++)
      bf[j] = *(const short8*)&Bs[(noff + j * 16 + l15) * 32 + quad * 8];
#pragma unroll
    for (int i = 0; i < 4; i++)
#pragma unroll
      for (int j = 0; j < 4; j++) acc[i][j] = MFMA_BF16(af[i], bf[j], acc[i][j]);
  }
  const float* bias = (n0 < D_) ? bq : bk;
  unsigned short* outp = (n0 < D_) ? outQ : outK;
  const int nn0 = n0 & (D_ - 1);
#pragma unroll
  for (int i = 0; i < 4; i++) {
    int row = m0 + moff + i * 16 + quad * 4;
#pragma unroll
    for (int j = 0; j < 4; j++) {
      int col = nn0 + noff + j * 16 + l15;
      float bb = bias[col];
#pragma unroll
      for (int g = 0; g < 4; g++)
        outp[(size_t)(row + g) * D_ + col] = f2b(acc[i][j][g] + bb);
    }
  }
}

// ---------------- fused post: vtrans | cw ----------------
// grid 1D: [0,2048) vtrans tiles; [2048,2176) cw
__global__ __launch_bounds__(256) void post_kernel(const unsigned short* __restrict__ v,
                                                   unsigned short* __restrict__ vt,
                                                   const unsigned short* __restrict__ p,
                                                   const float* __restrict__ ub,
                                                   const float* __restrict__ vbb,
                                                   float* __restrict__ cw) {
  __shared__ __align__(16) unsigned short t[64 * 72];
  int bid = blockIdx.x;
  int tid = threadIdx.x;
  if (bid < 2048) {
    int s0 = (bid & 31) * 64, h = (bid >> 5) & 15, b = bid >> 9;
#pragma unroll
    for (int c = 0; c < 2; c++) {
      int idx = tid + c * 256;
      int r = idx >> 3, ch = (idx & 7) * 8;
      short8 d = *(const short8*)(v + (((size_t)b * S_ + s0 + r) * H_ + h) * DH_ + ch);
      *(short8*)&t[r * 72 + ch] = d;
    }
    __syncthreads();
    int dh = tid >> 2, ch = tid & 3;
    unsigned short tmp[8];
#pragma unroll
    for (int half = 0; half < 2; half++) {
#pragma unroll
      for (int e = 0; e < 8; e++) tmp[e] = t[(ch * 16 + half * 8 + e) * 72 + dh];
      *(short8*)(vt + ((size_t)(b * H_ + h) * 64 + dh) * S_ + s0 + ch * 16 + half * 8) =
          *(short8*)tmp;
    }
    return;
  }
  int idx = (bid - 2048) * 256 + tid;  // [0, H*S)
  int r = idx & (S_ - 1), h = idx >> 11;
  float s = 0.f;
#pragma unroll 8
  for (int c = 0; c < 64; c++)
    s += (vbb[h * 64 + c] - ub[h * 64 + c]) * b2f(p[(size_t)r * D_ + h * 64 + c]);
  cw[idx] = s;
}

// ---------------- MFMA flash attention with rel-shift (transposed score) -------
// R6: all K/p/V staging via global_load_lds (async DMA, no reg round-trip, no
// commit phase). ps/vts double-buffered (issued at loop top, latency covered by
// full body); ks single-buffered (issued right after barrier1). ks/ps use
// chunk-XOR swizzle (LDS[r][pc] holds logical chunk pc^(r&7), via permuted
// per-lane GLOBAL source) to keep pitch-64 linear dest conflict-free. vts is
// pitch-32 linear (m97 GEMM read pattern). LDS 51200 B -> 3 blocks/CU.
__global__ __launch_bounds__(256) void attn_kernel(const unsigned short* __restrict__ q,
                                                   const unsigned short* __restrict__ kg,
                                                   const unsigned short* __restrict__ vtg,
                                                   const unsigned short* __restrict__ pg,
                                                   const float* __restrict__ ub,
                                                   const float* __restrict__ cw,
                                                   unsigned short* __restrict__ ctx) {
  // XCD-bijective swizzle (nwg = 2048 = 8*256)
  int flat = blockIdx.x + 32 * (blockIdx.y + 16 * blockIdx.z);
  int swz = (flat & 7) * 256 + (flat >> 3);
  const int i0 = (swz & 31) * 64;
  const int h = (swz >> 5) & 15;
  const int b = swz >> 9;
  const int tid = threadIdx.x;
  const int wid = tid >> 6, lane = tid & 63, quad = lane >> 4, l15 = lane & 15;
  const int wr0 = wid * 16;
  const int ib = i0 >> 5;  // first mixed jt

  __shared__ __align__(16) unsigned short ks[32 * 64];      // K tile, swizzled chunks
  __shared__ __align__(16) unsigned short ps[2][32 * 64];   // p rows dbuf, swizzled
  __shared__ __align__(16) unsigned short vts[2][64 * 32];  // V^T dbuf, linear
  __shared__ __align__(16) unsigned short prb[64 * 40];     // probs [i][j]
  __shared__ __align__(16) unsigned short bandA[64 * 100];  // ring, col mod96(r+1)
  __shared__ __align__(16) unsigned short bandB[64 * 100];  // ring, col mod96(r+2)

  const int srow = tid >> 3;                  // K/p staging row 0..31
  const int lcS = ((tid & 7) ^ (srow & 7)) * 8;  // swizzled logical chunk (u16 off)
  const int vrow = tid >> 2, vch = (tid & 3) * 8;  // V staging (linear)
  const int pc0 = (quad ^ (l15 & 7)) * 8;     // read-side physical chunk (u16 off)

  // global bases
  const unsigned short* kgl = kg + ((size_t)b * S_ * H_ + h) * DH_ + lcS;  // + j*H_*DH_
  const unsigned short* pgl = pg + h * 64 + lcS;                           // + rc*D_
  const unsigned short* vgl = vtg + ((size_t)(b * H_ + h) * 64 + vrow) * S_ + vch;  // + j
  const float* cwh = cw + h * S_;
  // LDS wave-uniform staging bases (u16 index)
  const int wb = wid * 512;  // 64 chunks * 8 u16

  // ---- direct q + u_bias fragment loads (one-time) ----
  short8 qa00, qa01, qa10, qa11;
  {
    auto ldq = [&](int r, int c0) -> short8 {
      int qi = i0 + r; if (qi > S_ - 1) qi = S_ - 1;
      short8 raw = *(const short8*)(q + (((size_t)b * S_ + qi) * H_ + h) * DH_ + c0);
      unsigned short t[8];
#pragma unroll
      for (int e = 0; e < 8; e++)
        t[e] = f2b(b2f((unsigned short)raw[e]) + ub[h * 64 + c0 + e]);
      return *(short8*)t;
    };
    qa00 = ldq(wr0 + l15, quad * 8);
    qa01 = ldq(wr0 + l15, 32 + quad * 8);
    qa10 = ldq(wr0 + l15 + 1, quad * 8);
    qa11 = ldq(wr0 + l15 + 1, 32 + quad * 8);
  }

  const int brow = (wr0 + l15) * 100;  // own band row (write AND read)

  // band MFMA, swapped operands; src = ps buffer (pitch 64, swizzled chunks)
  auto band_compute = [&](const unsigned short* src, int w, int rhi) {
    int rbase = rhi - 31;
    short8 a0 = w ? qa10 : qa00;
    short8 a1 = w ? qa11 : qa01;
    unsigned short* band = w ? bandB : bandA;
    const int OFF = w ? 2 : 1;
#pragma unroll
    for (int ct = 0; ct < 2; ct++) {
      int ro = (ct * 16 + l15) * 64;
      short8 b0 = *(const short8*)&src[ro + pc0];
      short8 b1 = *(const short8*)&src[ro + (pc0 ^ 32)];
      f32x4 acc = (f32x4){0.f, 0.f, 0.f, 0.f};
      acc = MFMA_BF16(b0, a0, acc);   // A = p rows, B = q rows
      acc = MFMA_BF16(b1, a1, acc);
      int r0 = rbase + ct * 16 + quad * 4;
      float c0 = cwh[clampS(r0)];
      float c1 = cwh[clampS(r0 + 1)];
      float c2 = cwh[clampS(r0 + 2)];
      float c3 = cwh[clampS(r0 + 3)];
      int col = mod96(r0 + 960 + OFF);   // === 0 mod 4 -> b64 aligned
      uint2 pv = make_uint2(pk2(acc[0] + c0, acc[1] + c1), pk2(acc[2] + c2, acc[3] + c3));
      *(uint2*)&band[brow + col] = pv;
      if (col == 0) *(uint2*)&band[brow + 96] = pv;  // mirror guard 96..99
    }
  };

  // ---- prologue: stage K(0), V(0), then 5 band backfill tasks via gload ----
  {
    const int TW[5] = {0, 0, 0, 1, 1};
    const int TR[5] = {S_ + 30 - i0 - 64, S_ + 30 - i0 - 32, S_ + 30 - i0, 29, 61};
    {
      int rc = clampS(TR[0] - 31 + srow);
      gload_lds16(pgl + (size_t)rc * D_, &ps[0][wb]);
      gload_lds16(kgl + (size_t)srow * (H_ * DH_), &ks[wb]);
      gload_lds16(vgl, &vts[0][wb]);
    }
    __syncthreads();
#pragma unroll
    for (int t = 0; t < 5; t++) {
      if (t < 4) {
        int rc = clampS(TR[t + 1] - 31 + srow);
        gload_lds16(pgl + (size_t)rc * D_, &ps[(t + 1) & 1][wb]);
      }
      band_compute(ps[t & 1], TW[t], TR[t]);
      __syncthreads();
    }
  }

  float lsum = 0.f;  // per thread: i = i0 + wr0 + l15 fixed
  f32x4 Oa[4];
#pragma unroll
  for (int ct = 0; ct < 4; ct++) Oa[ct] = (f32x4){0.f, 0.f, 0.f, 0.f};

  // ring cols for (g=0, ct=0), advance +32 mod 96 / jt; include OFF rotation
  int cA = mod96(S_ + quad * 4 - i0 - wr0 - l15);          // OFF_A=1 folded in
  int cB = mod96(2112 + quad * 4 - i0 - wr0 - l15);        // OFF_B=2 folded in
  int cwin = 0, crhi = 0, chave = 0;

  const float SCL = 0.03125f;
  const unsigned int prbw = (wr0 + l15) * 40 + quad * 4;

  for (int jt = 0; jt < 64; jt++) {
    const int j0 = jt * 32;
    const int cur = jt & 1, nxt = cur ^ 1;
    // ---- issue async stages for tile jt+1 (ps, vts) into the other buffers ----
    int pwin = 0, prhi = 0, havep = 0;
    {
      int j0x = j0 + 32;
      if (j0x <= i0 + 63) { pwin = 0; prhi = S_ + 30 - i0 + j0x; havep = 1; }
      else if (jt < 63)   { pwin = 1; prhi = j0x - i0 + 29;      havep = 1; }
      if (havep) {
        int rc = clampS(prhi - 31 + srow);
        gload_lds16(pgl + (size_t)rc * D_, &ps[nxt][wb]);
      }
      if (jt < 63)
        gload_lds16(vgl + (size_t)(j0 + 32), &vts[nxt][wb]);
    }
    // ---- band MFMA for task(jt), staged at jt-1 ----
    if (chave) band_compute(ps[cur], cwin, crhi);
    // ---- content MFMA, transposed: Sc^T rows=j, cols=i (ks swizzled reads) ----
    f32x4 cc[2];
    {
#pragma unroll
      for (int ct = 0; ct < 2; ct++) {
        int ro = (ct * 16 + l15) * 64;
        short8 a0 = *(const short8*)&ks[ro + pc0];
        short8 a1 = *(const short8*)&ks[ro + (pc0 ^ 32)];
        f32x4 acc = (f32x4){0.f, 0.f, 0.f, 0.f};
        acc = MFMA_BF16(a0, qa00, acc);
        acc = MFMA_BF16(a1, qa01, acc);
        cc[ct] = acc;
      }
    }
    __syncthreads();  // all waves done reading ks; drains top gloads
    // ---- issue K(jt+1) into ks (single buffer, safe after barrier) ----
    if (jt < 63)
      gload_lds16(kgl + (size_t)(j0 + 32 + srow) * (H_ * DH_), &ks[wb]);
    // ---- score: thread = (i fixed, j = j0 + ct*16 + quad*4 + g) ----
    if (jt < ib) {
#pragma unroll
      for (int ct = 0; ct < 2; ct++) {
        int c0 = ct ? (cA + 16 >= 96 ? cA + 16 - 96 : cA + 16) : cA;
        const unsigned short* base = &bandA[brow + c0];
        float e0 = __expf((cc[ct][0] + b2f(base[0])) * SCL);
        float e1 = __expf((cc[ct][1] + b2f(base[1])) * SCL);
        float e2 = __expf((cc[ct][2] + b2f(base[2])) * SCL);
        float e3 = __expf((cc[ct][3] + b2f(base[3])) * SCL);
        *(uint2*)&prb[prbw + ct * 16] = make_uint2(pk2(e0, e1), pk2(e2, e3));
        lsum += (e0 + e1) + (e2 + e3);
      }
    } else if (jt >= ib + 3) {
#pragma unroll
      for (int ct = 0; ct < 2; ct++) {
        int c0 = ct ? (cB + 16 >= 96 ? cB + 16 - 96 : cB + 16) : cB;
        const unsigned short* base = &bandB[brow + c0];
        float e0 = __expf((cc[ct][0] + b2f(base[0])) * SCL);
        float e1 = __expf((cc[ct][1] + b2f(base[1])) * SCL);
        float e2 = __expf((cc[ct][2] + b2f(base[2])) * SCL);
        float e3 = __expf((cc[ct][3] + b2f(base[3])) * SCL);
        *(uint2*)&prb[prbw + ct * 16] = make_uint2(pk2(e0, e1), pk2(e2, e3));
        lsum += (e0 + e1) + (e2 + e3);
      }
    } else {
      // mixed: generic per element; OFF rotation applied (A:+1, B:+2)
#pragma unroll
      for (int ct = 0; ct < 2; ct++) {
        int jbase = j0 + ct * 16 + quad * 4;
        float ev[4];
#pragma unroll
        for (int g = 0; g < 4; g++) {
          int d = jbase + g - (i0 + wr0 + l15);
          float t;
          if (d == 1) t = 0.f;
          else if (d <= 0) t = b2f(bandA[brow + mod96(S_ + d)]);      // r=S-1+d, +1
          else t = b2f(bandB[brow + mod96(d)]);                        // r=d-2, +2
          ev[g] = __expf((cc[ct][g] + t) * SCL);
          lsum += ev[g];
        }
        *(uint2*)&prb[prbw + ct * 16] = make_uint2(pk2(ev[0], ev[1]), pk2(ev[2], ev[3]));
      }
    }
    // ---- PV MFMA: O[i 16][dh 64] += P(16x32) @ V(32x64); V from vts[cur] ----
    {
      short8 af = *(const short8*)&prb[(wr0 + l15) * 40 + quad * 8];
#pragma unroll
      for (int ct = 0; ct < 4; ct++) {
        short8 bf = *(const short8*)&vts[cur][(ct * 16 + l15) * 32 + quad * 8];
        Oa[ct] = MFMA_BF16(af, bf, Oa[ct]);
      }
    }
    __syncthreads();  // drains K/p/V gloads; syncs for next iteration
    cwin = pwin; crhi = prhi; chave = havep;
    cA += 32; if (cA >= 96) cA -= 96;
    cB += 32; if (cB >= 96) cB -= 96;
  }
  // ---- epilogue ----
  float ltot = lsum;
  ltot += __shfl_xor(ltot, 16);
  ltot += __shfl_xor(ltot, 32);
#pragma unroll
  for (int g = 0; g < 4; g++) {
    float lg = __shfl(ltot, quad * 4 + g);
    float inv = 1.f / lg;
    int i = i0 + wr0 + quad * 4 + g;
    unsigned short* dst = ctx + ((size_t)b * S_ + i) * D_ + h * 64;
#pragma unroll
    for (int ct = 0; ct < 4; ct++) dst[ct * 16 + l15] = f2b(Oa[ct][g] * inv);
  }
}

extern "C" void kernel_launch(void* const* d_in, const int* in_sizes, int n_in,
                              void* d_out, int out_size, void* d_ws, size_t ws_size,
                              hipStream_t stream) {
  const float* inputs = (const float*)d_in[0];
  const float* pre_block = (const float*)d_in[1];
  const float* ln_gamma = (const float*)d_in[2];
  const float* ln_beta = (const float*)d_in[3];
  const float* Wq = (const float*)d_in[4];
  const float* bq = (const float*)d_in[5];
  const float* Wk = (const float*)d_in[6];
  const float* bk = (const float*)d_in[7];
  const float* Wv = (const float*)d_in[8];
  const float* bv = (const float*)d_in[9];
  const float* Wpos = (const float*)d_in[10];
  const float* u_bias = (const float*)d_in[11];
  const float* v_bias = (const float*)d_in[12];
  const float* Wo = (const float*)d_in[13];
  const float* bo = (const float*)d_in[14];
  float* out = (float*)d_out;

  char* ws = (char*)d_ws;
  const size_t NBS = (size_t)B_ * S_ * D_;  // 8388608
  unsigned short* xb = (unsigned short*)ws;
  unsigned short* ctx = (unsigned short*)ws;               // alias (xb dead after qk-GEMM)
  unsigned short* preb = (unsigned short*)(ws + NBS * 2);
  unsigned short* peb = (unsigned short*)(ws + NBS * 4);
  char* base = ws + NBS * 4 + (size_t)S_ * D_ * 2;
  unsigned short* wtq = (unsigned short*)(base);           // wtq||wtk contiguous (fused QK)
  unsigned short* wtk = (unsigned short*)(base + (size_t)D_ * D_ * 2);
  unsigned short* wtv = (unsigned short*)(base + (size_t)D_ * D_ * 4);
  unsigned short* wtp = (unsigned short*)(base + (size_t)D_ * D_ * 6);
  unsigned short* wto = (unsigned short*)(base + (size_t)D_ * D_ * 8);
  unsigned short* qb = (unsigned short*)(base + (size_t)D_ * D_ * 10);
  unsigned short* kb = qb + NBS;
  unsigned short* vb = kb + NBS;
  unsigned short* vtb = vb + NBS;
  unsigned short* pb = vtb + NBS;
  float* cww = (float*)(pb + (size_t)S_ * D_);
  double* divtab = (double*)(cww + (size_t)H_ * S_);  // dedicated 4KB slot

  // host-computed f64 div table (512 exps once; async H2D, graph-capture safe)
  static double h_divtab[512];
  static bool h_init = false;
  if (!h_init) {
    for (int i = 0; i < 512; i++)
      h_divtab[i] = exp(-(log(10000.0) * (2.0 * i) / (double)D_));
    h_init = true;
  }
  hipMemcpyAsync(divtab, h_divtab, 512 * sizeof(double), hipMemcpyHostToDevice, stream);

  prep_kernel<<<21760, 256, 0, stream>>>(inputs, ln_gamma, ln_beta, xb,
                                         pre_block, preb, divtab, peb,
                                         Wq, wtq, Wk, wtk, Wv, wtv, Wpos, wtp, Wo, wto);
  gemm_qk_bf16<<<dim3(16, 64), 256, 0, stream>>>(xb, wtq, bq, bk, qb, kb);
  gemm_bf16_t<false><<<dim3(8, 64), 256, 0, stream>>>(preb, wtv, bv, vb, B_ * S_, D_, D_);
  gemm_bf16_t<false><<<dim3(8, 16), 256, 0, stream>>>(peb, wtp, nullptr, pb, S_, D_, D_);
  post_kernel<<<2176, 256, 0, stream>>>(vb, vtb, pb, u_bias, v_bias, cww);
  attn_kernel<<<dim3(32, 16, 4), 256, 0, stream>>>(qb, kb, vtb, pb, u_bias, cww, ctx);
  gemm_bf16_t<true><<<dim3(8, 64), 256, 0, stream>>>(ctx, wto, bo, out, B_ * S_, D_, D_);
}

// Round 8
// 614.552 us; speedup vs baseline: 1.1312x; 1.0334x over previous
//
#include <hip/hip_runtime.h>
#include <hip/hip_bf16.h>
#include <cmath>

#define B_ 4
#define S_ 2048
#define D_ 1024
#define H_ 16
#define DH_ 64

typedef __attribute__((ext_vector_type(8))) short short8;
typedef __attribute__((ext_vector_type(4))) float f32x4;
#define MFMA_BF16(a, b, c) __builtin_amdgcn_mfma_f32_16x16x32_bf16(a, b, c, 0, 0, 0)

static __device__ __forceinline__ float b2f(unsigned short u) {
  union { unsigned int i; float f; } x; x.i = ((unsigned int)u) << 16; return x.f;
}
static __device__ __forceinline__ unsigned short f2b(float f) {
  union { float f; unsigned int i; } x; x.f = f;
  unsigned int r = x.i + 0x7FFFu + ((x.i >> 16) & 1u);
  return (unsigned short)(r >> 16);
}
// packed 2x f32 -> 2x bf16 (RNE), low = a
static __device__ __forceinline__ unsigned int pk2(float a, float b) {
  __hip_bfloat162 h = __float22bfloat162_rn(make_float2(a, b));
  return *(unsigned int*)&h;
}
// exact x mod 96 for 0 <= x < ~1e6
static __device__ __forceinline__ int mod96(int x) {
  int t = x >> 5;
  int q = (t * 43691) >> 17;  // floor(t/3), exact for t < 32768
  int m3 = t - q * 3;
  return (x & 31) + (m3 << 5);
}
static __device__ __forceinline__ int clampS(int x) {
  return x < 0 ? 0 : (x > S_ - 1 ? S_ - 1 : x);
}
// async global->LDS, 16B per lane; lds dest must be wave-uniform base (+lane*16)
typedef __attribute__((address_space(3))) unsigned int lds_u32_t;
typedef __attribute__((address_space(1))) const unsigned int glb_u32_t;
static __device__ __forceinline__ void gload_lds16(const void* g, void* l) {
  __builtin_amdgcn_global_load_lds((glb_u32_t*)g, (lds_u32_t*)l, 16, 0, 0);
}

// ---------------- fused prep: ln | cast | pe | wtrans x5 ----------------
// grid 1D: [0,8192) ln rows; [8192,16384) cast; [16384,20480) pe; [20480,21760) wtrans
__global__ __launch_bounds__(256) void prep_kernel(
    const float* __restrict__ inputs, const float* __restrict__ gamma,
    const float* __restrict__ beta, unsigned short* __restrict__ xb,
    const float* __restrict__ pre, unsigned short* __restrict__ preb,
    const double* __restrict__ dt, unsigned short* __restrict__ pe,
    const float* __restrict__ Wq, unsigned short* __restrict__ wtq,
    const float* __restrict__ Wk, unsigned short* __restrict__ wtk,
    const float* __restrict__ Wv, unsigned short* __restrict__ wtv,
    const float* __restrict__ Wp, unsigned short* __restrict__ wtp,
    const float* __restrict__ Wo, unsigned short* __restrict__ wto) {
  __shared__ __align__(16) float shf[64 * 65];  // wtrans tile; ln aliases head
  int bid = blockIdx.x;
  int tid = threadIdx.x;
  if (bid < 8192) {
    // ---- LayerNorm -> bf16 ----
    int row = bid;
    float4 val = ((const float4*)(inputs + (size_t)row * D_))[tid];
    float s = val.x + val.y + val.z + val.w;
    float sq = val.x * val.x + val.y * val.y + val.z * val.z + val.w * val.w;
#pragma unroll
    for (int o = 32; o > 0; o >>= 1) {
      s += __shfl_down(s, o);
      sq += __shfl_down(sq, o);
    }
    int wid = tid >> 6;
    if ((tid & 63) == 0) { shf[wid] = s; shf[4 + wid] = sq; }
    __syncthreads();
    if (tid == 0) {
      float ts = shf[0] + shf[1] + shf[2] + shf[3];
      float tq = shf[4] + shf[5] + shf[6] + shf[7];
      float mu = ts * (1.0f / D_);
      float var = tq * (1.0f / D_) - mu * mu;
      shf[8] = mu;
      shf[9] = rsqrtf(var + 1e-5f);
    }
    __syncthreads();
    float mu = shf[8], rs = shf[9];
    float4 g = ((const float4*)gamma)[tid];
    float4 be = ((const float4*)beta)[tid];
    ushort4 o;
    o.x = f2b((val.x - mu) * rs * g.x + be.x);
    o.y = f2b((val.y - mu) * rs * g.y + be.y);
    o.z = f2b((val.z - mu) * rs * g.z + be.z);
    o.w = f2b((val.w - mu) * rs * g.w + be.w);
    *(ushort4*)(xb + (size_t)row * D_ + tid * 4) = o;
    return;
  }
  bid -= 8192;
  if (bid < 8192) {
    // ---- fp32 -> bf16 cast ----
    size_t idx = (size_t)(bid * 256 + tid) * 4;
    float4 v = *(const float4*)(pre + idx);
    ushort4 o; o.x = f2b(v.x); o.y = f2b(v.y); o.z = f2b(v.z); o.w = f2b(v.w);
    *(ushort4*)(preb + idx) = o;
    return;
  }
  bid -= 8192;
  if (bid < 4096) {
    // ---- sinusoidal PE -> bf16 (f64 table angle + f32 sincos) ----
    int idx = bid * 256 + tid;  // [0, S*D/2)
    int t = idx >> 9;
    int i = idx & 511;
    double ang = (double)t * dt[i];
    double k = floor(ang * 0.15915494309189535);
    float red = (float)(ang - k * 6.283185307179586);
    ushort2 sc;
    sc.x = f2b(sinf(red));
    sc.y = f2b(cosf(red));
    *(ushort2*)(pe + (size_t)t * D_ + 2 * i) = sc;
    return;
  }
  bid -= 4096;
  // ---- W[K,N] fp32 -> WT[N,K] bf16 (64x64 tiles) ----
  const float* W; unsigned short* WT;
  switch (bid >> 8) {
    case 0: W = Wq; WT = wtq; break;
    case 1: W = Wk; WT = wtk; break;
    case 2: W = Wv; WT = wtv; break;
    case 3: W = Wp; WT = wtp; break;
    default: W = Wo; WT = wto; break;
  }
  int tile = bid & 255;
  int n0 = (tile & 15) * 64, k0 = (tile >> 4) * 64;
#pragma unroll
  for (int c = 0; c < 4; c++) {
    int idx = tid + c * 256;
    int r = idx >> 4;
    int ch = (idx & 15) * 4;
    float4 d = *(const float4*)(W + (size_t)(k0 + r) * D_ + n0 + ch);
    shf[r * 65 + ch] = d.x; shf[r * 65 + ch + 1] = d.y;
    shf[r * 65 + ch + 2] = d.z; shf[r * 65 + ch + 3] = d.w;
  }
  __syncthreads();
  {
    int n = tid >> 2;
    int ch = (tid & 3) * 16;
    unsigned short tmp[8];
#pragma unroll
    for (int half = 0; half < 2; half++) {
#pragma unroll
      for (int e = 0; e < 8; e++) tmp[e] = f2b(shf[(ch + half * 8 + e) * 65 + n]);
      *(short8*)(WT + (size_t)(n0 + n) * D_ + k0 + ch + half * 8) = *(short8*)tmp;
    }
  }
}

// ---------------- bf16 MFMA GEMM: C[M,N] = A[M,K] @ BT[N,K]^T + bias ----------------
template <bool F32OUT>
__global__ __launch_bounds__(256) void gemm_bf16_t(const unsigned short* __restrict__ A,
                                                   const unsigned short* __restrict__ BT,
                                                   const float* __restrict__ bias,
                                                   void* __restrict__ Cv,
                                                   int M, int N, int K) {
  __shared__ __align__(16) unsigned short As[128 * 32];
  __shared__ __align__(16) unsigned short Bs[128 * 32];
  const int tid = threadIdx.x;
  const int wid = tid >> 6, lane = tid & 63, quad = lane >> 4, l15 = lane & 15;
  const int m0 = blockIdx.y * 128, n0 = blockIdx.x * 128;
  const int moff = (wid >> 1) * 64, noff = (wid & 1) * 64;
  f32x4 acc[4][4];
#pragma unroll
  for (int i = 0; i < 4; i++)
#pragma unroll
    for (int j = 0; j < 4; j++) acc[i][j] = (f32x4){0.f, 0.f, 0.f, 0.f};

  const int cb0 = wid * 64;
  const int c0 = cb0 + lane;
  const int r0 = c0 >> 2, ch0 = (c0 & 3) * 8;
  const int c1 = c0 + 256;
  const int r1 = c1 >> 2, ch1 = (c1 & 3) * 8;

  for (int k0 = 0; k0 < K; k0 += 32) {
    __syncthreads();
    gload_lds16(A + (size_t)(m0 + r0) * K + k0 + ch0, &As[cb0 * 8]);
    gload_lds16(BT + (size_t)(n0 + r0) * K + k0 + ch0, &Bs[cb0 * 8]);
    gload_lds16(A + (size_t)(m0 + r1) * K + k0 + ch1, &As[(cb0 + 256) * 8]);
    gload_lds16(BT + (size_t)(n0 + r1) * K + k0 + ch1, &Bs[(cb0 + 256) * 8]);
    __syncthreads();
    short8 af[4], bf[4];
#pragma unroll
    for (int i = 0; i < 4; i++)
      af[i] = *(const short8*)&As[(moff + i * 16 + l15) * 32 + quad * 8];
#pragma unroll
    for (int j = 0; j < 4; j++)
      bf[j] = *(const short8*)&Bs[(noff + j * 16 + l15) * 32 + quad * 8];
#pragma unroll
    for (int i = 0; i < 4; i++)
#pragma unroll
      for (int j = 0; j < 4; j++) acc[i][j] = MFMA_BF16(af[i], bf[j], acc[i][j]);
  }
#pragma unroll
  for (int i = 0; i < 4; i++) {
    int row = m0 + moff + i * 16 + quad * 4;
#pragma unroll
    for (int j = 0; j < 4; j++) {
      int col = n0 + noff + j * 16 + l15;
      float bb = bias ? bias[col] : 0.f;
#pragma unroll
      for (int g = 0; g < 4; g++) {
        if (F32OUT)
          ((float*)Cv)[(size_t)(row + g) * N + col] = acc[i][j][g] + bb;
        else
          ((unsigned short*)Cv)[(size_t)(row + g) * N + col] = f2b(acc[i][j][g] + bb);
      }
    }
  }
}

// ---------------- fused Q+K GEMM: BT = [wtq ; wtk] (2048 rows), N=2048 ----------------
__global__ __launch_bounds__(256) void gemm_qk_bf16(const unsigned short* __restrict__ A,
                                                    const unsigned short* __restrict__ BT,
                                                    const float* __restrict__ bq,
                                                    const float* __restrict__ bk,
                                                    unsigned short* __restrict__ outQ,
                                                    unsigned short* __restrict__ outK) {
  const int K = D_;
  __shared__ __align__(16) unsigned short As[128 * 32];
  __shared__ __align__(16) unsigned short Bs[128 * 32];
  const int tid = threadIdx.x;
  const int wid = tid >> 6, lane = tid & 63, quad = lane >> 4, l15 = lane & 15;
  const int m0 = blockIdx.y * 128, n0 = blockIdx.x * 128;
  const int moff = (wid >> 1) * 64, noff = (wid & 1) * 64;
  f32x4 acc[4][4];
#pragma unroll
  for (int i = 0; i < 4; i++)
#pragma unroll
    for (int j = 0; j < 4; j++) acc[i][j] = (f32x4){0.f, 0.f, 0.f, 0.f};

  const int cb0 = wid * 64;
  const int c0 = cb0 + lane;
  const int r0 = c0 >> 2, ch0 = (c0 & 3) * 8;
  const int c1 = c0 + 256;
  const int r1 = c1 >> 2, ch1 = (c1 & 3) * 8;

  for (int k0 = 0; k0 < K; k0 += 32) {
    __syncthreads();
    gload_lds16(A + (size_t)(m0 + r0) * K + k0 + ch0, &As[cb0 * 8]);
    gload_lds16(BT + (size_t)(n0 + r0) * K + k0 + ch0, &Bs[cb0 * 8]);
    gload_lds16(A + (size_t)(m0 + r1) * K + k0 + ch1, &As[(cb0 + 256) * 8]);
    gload_lds16(BT + (size_t)(n0 + r1) * K + k0 + ch1, &Bs[(cb0 + 256) * 8]);
    __syncthreads();
    short8 af[4], bf[4];
#pragma unroll
    for (int i = 0; i < 4; i++)
      af[i] = *(const short8*)&As[(moff + i * 16 + l15) * 32 + quad * 8];
#pragma unroll
    for (int j = 0; j < 4; j++)
      bf[j] = *(const short8*)&Bs[(noff + j * 16 + l15) * 32 + quad * 8];
#pragma unroll
    for (int i = 0; i < 4; i++)
#pragma unroll
      for (int j = 0; j < 4; j++) acc[i][j] = MFMA_BF16(af[i], bf[j], acc[i][j]);
  }
  const float* bias = (n0 < D_) ? bq : bk;
  unsigned short* outp = (n0 < D_) ? outQ : outK;
  const int nn0 = n0 & (D_ - 1);
#pragma unroll
  for (int i = 0; i < 4; i++) {
    int row = m0 + moff + i * 16 + quad * 4;
#pragma unroll
    for (int j = 0; j < 4; j++) {
      int col = nn0 + noff + j * 16 + l15;
      float bb = bias[col];
#pragma unroll
      for (int g = 0; g < 4; g++)
        outp[(size_t)(row + g) * D_ + col] = f2b(acc[i][j][g] + bb);
    }
  }
}

// ---------------- post: vtrans only (cw eliminated algebraically) ----------------
__global__ __launch_bounds__(256) void post_kernel(const unsigned short* __restrict__ v,
                                                   unsigned short* __restrict__ vt) {
  __shared__ __align__(16) unsigned short t[64 * 72];
  int bid = blockIdx.x;
  int tid = threadIdx.x;
  int s0 = (bid & 31) * 64, h = (bid >> 5) & 15, b = bid >> 9;
#pragma unroll
  for (int c = 0; c < 2; c++) {
    int idx = tid + c * 256;
    int r = idx >> 3, ch = (idx & 7) * 8;
    short8 d = *(const short8*)(v + (((size_t)b * S_ + s0 + r) * H_ + h) * DH_ + ch);
    *(short8*)&t[r * 72 + ch] = d;
  }
  __syncthreads();
  int dh = tid >> 2, ch = tid & 3;
  unsigned short tmp[8];
#pragma unroll
  for (int half = 0; half < 2; half++) {
#pragma unroll
    for (int e = 0; e < 8; e++) tmp[e] = t[(ch * 16 + half * 8 + e) * 72 + dh];
    *(short8*)(vt + ((size_t)(b * H_ + h) * 64 + dh) * S_ + s0 + ch * 16 + half * 8) =
        *(short8*)tmp;
  }
}

// ---------------- MFMA flash attention with rel-shift (transposed score) -------
// R8 (= R7 resubmit after infra failure): cw term eliminated algebraically --
// band MFMA uses (q+v_bias) fragments directly ((q+u).p + (v-u).p === (q+v).p,
// same p-row clamp -> bit-identical). Removes 8 scattered VMEM gathers + clamps
// + adds per wave-jt, and the cw kernel/buffer entirely. s_setprio(1) wraps the
// MFMA cluster (T5).
__global__ __launch_bounds__(256) void attn_kernel(const unsigned short* __restrict__ q,
                                                   const unsigned short* __restrict__ kg,
                                                   const unsigned short* __restrict__ vtg,
                                                   const unsigned short* __restrict__ pg,
                                                   const float* __restrict__ ub,
                                                   const float* __restrict__ vbias,
                                                   unsigned short* __restrict__ ctx) {
  // XCD-bijective swizzle (nwg = 2048 = 8*256)
  int flat = blockIdx.x + 32 * (blockIdx.y + 16 * blockIdx.z);
  int swz = (flat & 7) * 256 + (flat >> 3);
  const int i0 = (swz & 31) * 64;
  const int h = (swz >> 5) & 15;
  const int b = swz >> 9;
  const int tid = threadIdx.x;
  const int wid = tid >> 6, lane = tid & 63, quad = lane >> 4, l15 = lane & 15;
  const int wr0 = wid * 16;
  const int ib = i0 >> 5;  // first mixed jt

  __shared__ __align__(16) unsigned short ks[32 * 64];      // K tile, swizzled chunks
  __shared__ __align__(16) unsigned short ps[2][32 * 64];   // p rows dbuf, swizzled
  __shared__ __align__(16) unsigned short vts[2][64 * 32];  // V^T dbuf, linear
  __shared__ __align__(16) unsigned short prb[64 * 40];     // probs [i][j]
  __shared__ __align__(16) unsigned short bandA[64 * 100];  // ring, col mod96(r+1)
  __shared__ __align__(16) unsigned short bandB[64 * 100];  // ring, col mod96(r+2)

  const int srow = tid >> 3;                  // K/p staging row 0..31
  const int lcS = ((tid & 7) ^ (srow & 7)) * 8;  // swizzled logical chunk (u16 off)
  const int vrow = tid >> 2, vch = (tid & 3) * 8;  // V staging (linear)
  const int pc0 = (quad ^ (l15 & 7)) * 8;     // read-side physical chunk (u16 off)

  // global bases
  const unsigned short* kgl = kg + ((size_t)b * S_ * H_ + h) * DH_ + lcS;  // + j*H_*DH_
  const unsigned short* pgl = pg + h * 64 + lcS;                           // + rc*D_
  const unsigned short* vgl = vtg + ((size_t)(b * H_ + h) * 64 + vrow) * S_ + vch;  // + j
  // LDS wave-uniform staging bases (u16 index)
  const int wb = wid * 512;  // 64 chunks * 8 u16

  // ---- direct q fragment loads: (q+u) for content, (q+v) for bands ----
  short8 qc0, qc1, qA0, qA1, qB0, qB1;
  {
    auto ldq2 = [&](int r, int c0, short8& outU, short8& outV) {
      int qi = i0 + r; if (qi > S_ - 1) qi = S_ - 1;
      short8 raw = *(const short8*)(q + (((size_t)b * S_ + qi) * H_ + h) * DH_ + c0);
      unsigned short tu[8], tv[8];
#pragma unroll
      for (int e = 0; e < 8; e++) {
        float f = b2f((unsigned short)raw[e]);
        tu[e] = f2b(f + ub[h * 64 + c0 + e]);
        tv[e] = f2b(f + vbias[h * 64 + c0 + e]);
      }
      outU = *(short8*)tu;
      outV = *(short8*)tv;
    };
    auto ldqv = [&](int r, int c0) -> short8 {
      int qi = i0 + r; if (qi > S_ - 1) qi = S_ - 1;
      short8 raw = *(const short8*)(q + (((size_t)b * S_ + qi) * H_ + h) * DH_ + c0);
      unsigned short tv[8];
#pragma unroll
      for (int e = 0; e < 8; e++)
        tv[e] = f2b(b2f((unsigned short)raw[e]) + vbias[h * 64 + c0 + e]);
      return *(short8*)tv;
    };
    ldq2(wr0 + l15, quad * 8, qc0, qA0);
    ldq2(wr0 + l15, 32 + quad * 8, qc1, qA1);
    qB0 = ldqv(wr0 + l15 + 1, quad * 8);
    qB1 = ldqv(wr0 + l15 + 1, 32 + quad * 8);
  }

  const int brow = (wr0 + l15) * 100;  // own band row (write AND read)

  // band MFMA, swapped operands; src = ps buffer (pitch 64, swizzled chunks)
  auto band_compute = [&](const unsigned short* src, int w, int rhi) {
    int rbase = rhi - 31;
    short8 a0 = w ? qB0 : qA0;
    short8 a1 = w ? qB1 : qA1;
    unsigned short* band = w ? bandB : bandA;
    const int OFF = w ? 2 : 1;
#pragma unroll
    for (int ct = 0; ct < 2; ct++) {
      int ro = (ct * 16 + l15) * 64;
      short8 b0 = *(const short8*)&src[ro + pc0];
      short8 b1 = *(const short8*)&src[ro + (pc0 ^ 32)];
      f32x4 acc = (f32x4){0.f, 0.f, 0.f, 0.f};
      acc = MFMA_BF16(b0, a0, acc);   // A = p rows, B = (q+v) rows
      acc = MFMA_BF16(b1, a1, acc);
      int r0 = rbase + ct * 16 + quad * 4;
      int col = mod96(r0 + 960 + OFF);   // === 0 mod 4 -> b64 aligned
      uint2 pv = make_uint2(pk2(acc[0], acc[1]), pk2(acc[2], acc[3]));
      *(uint2*)&band[brow + col] = pv;
      if (col == 0) *(uint2*)&band[brow + 96] = pv;  // mirror guard 96..99
    }
  };

  // ---- prologue: stage K(0), V(0), then 5 band backfill tasks via gload ----
  {
    const int TW[5] = {0, 0, 0, 1, 1};
    const int TR[5] = {S_ + 30 - i0 - 64, S_ + 30 - i0 - 32, S_ + 30 - i0, 29, 61};
    {
      int rc = clampS(TR[0] - 31 + srow);
      gload_lds16(pgl + (size_t)rc * D_, &ps[0][wb]);
      gload_lds16(kgl + (size_t)srow * (H_ * DH_), &ks[wb]);
      gload_lds16(vgl, &vts[0][wb]);
    }
    __syncthreads();
#pragma unroll
    for (int t = 0; t < 5; t++) {
      if (t < 4) {
        int rc = clampS(TR[t + 1] - 31 + srow);
        gload_lds16(pgl + (size_t)rc * D_, &ps[(t + 1) & 1][wb]);
      }
      band_compute(ps[t & 1], TW[t], TR[t]);
      __syncthreads();
    }
  }

  float lsum = 0.f;  // per thread: i = i0 + wr0 + l15 fixed
  f32x4 Oa[4];
#pragma unroll
  for (int ct = 0; ct < 4; ct++) Oa[ct] = (f32x4){0.f, 0.f, 0.f, 0.f};

  // ring cols for (g=0, ct=0), advance +32 mod 96 / jt; include OFF rotation
  int cA = mod96(S_ + quad * 4 - i0 - wr0 - l15);          // OFF_A=1 folded in
  int cB = mod96(2112 + quad * 4 - i0 - wr0 - l15);        // OFF_B=2 folded in
  int cwin = 0, crhi = 0, chave = 0;

  const float SCL = 0.03125f;
  const unsigned int prbw = (wr0 + l15) * 40 + quad * 4;

  for (int jt = 0; jt < 64; jt++) {
    const int j0 = jt * 32;
    const int cur = jt & 1, nxt = cur ^ 1;
    // ---- issue async stages for tile jt+1 (ps, vts) into the other buffers ----
    int pwin = 0, prhi = 0, havep = 0;
    {
      int j0x = j0 + 32;
      if (j0x <= i0 + 63) { pwin = 0; prhi = S_ + 30 - i0 + j0x; havep = 1; }
      else if (jt < 63)   { pwin = 1; prhi = j0x - i0 + 29;      havep = 1; }
      if (havep) {
        int rc = clampS(prhi - 31 + srow);
        gload_lds16(pgl + (size_t)rc * D_, &ps[nxt][wb]);
      }
      if (jt < 63)
        gload_lds16(vgl + (size_t)(j0 + 32), &vts[nxt][wb]);
    }
    __builtin_amdgcn_s_setprio(1);
    // ---- band MFMA for task(jt), staged at jt-1 ----
    if (chave) band_compute(ps[cur], cwin, crhi);
    // ---- content MFMA, transposed: Sc^T rows=j, cols=i (ks swizzled reads) ----
    f32x4 cc[2];
    {
#pragma unroll
      for (int ct = 0; ct < 2; ct++) {
        int ro = (ct * 16 + l15) * 64;
        short8 a0 = *(const short8*)&ks[ro + pc0];
        short8 a1 = *(const short8*)&ks[ro + (pc0 ^ 32)];
        f32x4 acc = (f32x4){0.f, 0.f, 0.f, 0.f};
        acc = MFMA_BF16(a0, qc0, acc);
        acc = MFMA_BF16(a1, qc1, acc);
        cc[ct] = acc;
      }
    }
    __builtin_amdgcn_s_setprio(0);
    __syncthreads();  // all waves done reading ks; drains top gloads
    // ---- issue K(jt+1) into ks (single buffer, safe after barrier) ----
    if (jt < 63)
      gload_lds16(kgl + (size_t)(j0 + 32 + srow) * (H_ * DH_), &ks[wb]);
    // ---- score: thread = (i fixed, j = j0 + ct*16 + quad*4 + g) ----
    if (jt < ib) {
#pragma unroll
      for (int ct = 0; ct < 2; ct++) {
        int c0 = ct ? (cA + 16 >= 96 ? cA + 16 - 96 : cA + 16) : cA;
        const unsigned short* base = &bandA[brow + c0];
        float e0 = __expf((cc[ct][0] + b2f(base[0])) * SCL);
        float e1 = __expf((cc[ct][1] + b2f(base[1])) * SCL);
        float e2 = __expf((cc[ct][2] + b2f(base[2])) * SCL);
        float e3 = __expf((cc[ct][3] + b2f(base[3])) * SCL);
        *(uint2*)&prb[prbw + ct * 16] = make_uint2(pk2(e0, e1), pk2(e2, e3));
        lsum += (e0 + e1) + (e2 + e3);
      }
    } else if (jt >= ib + 3) {
#pragma unroll
      for (int ct = 0; ct < 2; ct++) {
        int c0 = ct ? (cB + 16 >= 96 ? cB + 16 - 96 : cB + 16) : cB;
        const unsigned short* base = &bandB[brow + c0];
        float e0 = __expf((cc[ct][0] + b2f(base[0])) * SCL);
        float e1 = __expf((cc[ct][1] + b2f(base[1])) * SCL);
        float e2 = __expf((cc[ct][2] + b2f(base[2])) * SCL);
        float e3 = __expf((cc[ct][3] + b2f(base[3])) * SCL);
        *(uint2*)&prb[prbw + ct * 16] = make_uint2(pk2(e0, e1), pk2(e2, e3));
        lsum += (e0 + e1) + (e2 + e3);
      }
    } else {
      // mixed: generic per element; OFF rotation applied (A:+1, B:+2)
#pragma unroll
      for (int ct = 0; ct < 2; ct++) {
        int jbase = j0 + ct * 16 + quad * 4;
        float ev[4];
#pragma unroll
        for (int g = 0; g < 4; g++) {
          int d = jbase + g - (i0 + wr0 + l15);
          float t;
          if (d == 1) t = 0.f;
          else if (d <= 0) t = b2f(bandA[brow + mod96(S_ + d)]);      // r=S-1+d, +1
          else t = b2f(bandB[brow + mod96(d)]);                        // r=d-2, +2
          ev[g] = __expf((cc[ct][g] + t) * SCL);
          lsum += ev[g];
        }
        *(uint2*)&prb[prbw + ct * 16] = make_uint2(pk2(ev[0], ev[1]), pk2(ev[2], ev[3]));
      }
    }
    // ---- PV MFMA: O[i 16][dh 64] += P(16x32) @ V(32x64); V from vts[cur] ----
    {
      short8 af = *(const short8*)&prb[(wr0 + l15) * 40 + quad * 8];
#pragma unroll
      for (int ct = 0; ct < 4; ct++) {
        short8 bf = *(const short8*)&vts[cur][(ct * 16 + l15) * 32 + quad * 8];
        Oa[ct] = MFMA_BF16(af, bf, Oa[ct]);
      }
    }
    __syncthreads();  // drains K/p/V gloads; syncs for next iteration
    cwin = pwin; crhi = prhi; chave = havep;
    cA += 32; if (cA >= 96) cA -= 96;
    cB += 32; if (cB >= 96) cB -= 96;
  }
  // ---- epilogue ----
  float ltot = lsum;
  ltot += __shfl_xor(ltot, 16);
  ltot += __shfl_xor(ltot, 32);
#pragma unroll
  for (int g = 0; g < 4; g++) {
    float lg = __shfl(ltot, quad * 4 + g);
    float inv = 1.f / lg;
    int i = i0 + wr0 + quad * 4 + g;
    unsigned short* dst = ctx + ((size_t)b * S_ + i) * D_ + h * 64;
#pragma unroll
    for (int ct = 0; ct < 4; ct++) dst[ct * 16 + l15] = f2b(Oa[ct][g] * inv);
  }
}

extern "C" void kernel_launch(void* const* d_in, const int* in_sizes, int n_in,
                              void* d_out, int out_size, void* d_ws, size_t ws_size,
                              hipStream_t stream) {
  const float* inputs = (const float*)d_in[0];
  const float* pre_block = (const float*)d_in[1];
  const float* ln_gamma = (const float*)d_in[2];
  const float* ln_beta = (const float*)d_in[3];
  const float* Wq = (const float*)d_in[4];
  const float* bq = (const float*)d_in[5];
  const float* Wk = (const float*)d_in[6];
  const float* bk = (const float*)d_in[7];
  const float* Wv = (const float*)d_in[8];
  const float* bv = (const float*)d_in[9];
  const float* Wpos = (const float*)d_in[10];
  const float* u_bias = (const float*)d_in[11];
  const float* v_bias = (const float*)d_in[12];
  const float* Wo = (const float*)d_in[13];
  const float* bo = (const float*)d_in[14];
  float* out = (float*)d_out;

  char* ws = (char*)d_ws;
  const size_t NBS = (size_t)B_ * S_ * D_;  // 8388608
  unsigned short* xb = (unsigned short*)ws;
  unsigned short* ctx = (unsigned short*)ws;               // alias (xb dead after qk-GEMM)
  unsigned short* preb = (unsigned short*)(ws + NBS * 2);
  unsigned short* peb = (unsigned short*)(ws + NBS * 4);
  char* base = ws + NBS * 4 + (size_t)S_ * D_ * 2;
  unsigned short* wtq = (unsigned short*)(base);           // wtq||wtk contiguous (fused QK)
  unsigned short* wtk = (unsigned short*)(base + (size_t)D_ * D_ * 2);
  unsigned short* wtv = (unsigned short*)(base + (size_t)D_ * D_ * 4);
  unsigned short* wtp = (unsigned short*)(base + (size_t)D_ * D_ * 6);
  unsigned short* wto = (unsigned short*)(base + (size_t)D_ * D_ * 8);
  unsigned short* qb = (unsigned short*)(base + (size_t)D_ * D_ * 10);
  unsigned short* kb = qb + NBS;
  unsigned short* vb = kb + NBS;
  unsigned short* vtb = vb + NBS;
  unsigned short* pb = vtb + NBS;
  double* divtab = (double*)(pb + (size_t)S_ * D_);  // dedicated 4KB slot

  // host-computed f64 div table (512 exps once; async H2D, graph-capture safe)
  static double h_divtab[512];
  static bool h_init = false;
  if (!h_init) {
    for (int i = 0; i < 512; i++)
      h_divtab[i] = exp(-(log(10000.0) * (2.0 * i) / (double)D_));
    h_init = true;
  }
  hipMemcpyAsync(divtab, h_divtab, 512 * sizeof(double), hipMemcpyHostToDevice, stream);

  prep_kernel<<<21760, 256, 0, stream>>>(inputs, ln_gamma, ln_beta, xb,
                                         pre_block, preb, divtab, peb,
                                         Wq, wtq, Wk, wtk, Wv, wtv, Wpos, wtp, Wo, wto);
  gemm_qk_bf16<<<dim3(16, 64), 256, 0, stream>>>(xb, wtq, bq, bk, qb, kb);
  gemm_bf16_t<false><<<dim3(8, 64), 256, 0, stream>>>(preb, wtv, bv, vb, B_ * S_, D_, D_);
  gemm_bf16_t<false><<<dim3(8, 16), 256, 0, stream>>>(peb, wtp, nullptr, pb, S_, D_, D_);
  post_kernel<<<2048, 256, 0, stream>>>(vb, vtb);
  attn_kernel<<<dim3(32, 16, 4), 256, 0, stream>>>(qb, kb, vtb, pb, u_bias, v_bias, ctx);
  gemm_bf16_t<true><<<dim3(8, 64), 256, 0, stream>>>(ctx, wto, bo, out, B_ * S_, D_, D_);
}

// Round 9
// 575.740 us; speedup vs baseline: 1.2075x; 1.0674x over previous
//
#include <hip/hip_runtime.h>
#include <hip/hip_bf16.h>
#include <cmath>

#define B_ 4
#define S_ 2048
#define D_ 1024
#define H_ 16
#define DH_ 64

typedef __attribute__((ext_vector_type(8))) short short8;
typedef __attribute__((ext_vector_type(4))) float f32x4;
#define MFMA_BF16(a, b, c) __builtin_amdgcn_mfma_f32_16x16x32_bf16(a, b, c, 0, 0, 0)

static __device__ __forceinline__ float b2f(unsigned short u) {
  union { unsigned int i; float f; } x; x.i = ((unsigned int)u) << 16; return x.f;
}
static __device__ __forceinline__ unsigned short f2b(float f) {
  union { float f; unsigned int i; } x; x.f = f;
  unsigned int r = x.i + 0x7FFFu + ((x.i >> 16) & 1u);
  return (unsigned short)(r >> 16);
}
// packed 2x f32 -> 2x bf16 (RNE), low = a
static __device__ __forceinline__ unsigned int pk2(float a, float b) {
  __hip_bfloat162 h = __float22bfloat162_rn(make_float2(a, b));
  return *(unsigned int*)&h;
}
// exact x mod 96 for 0 <= x < ~1e6
static __device__ __forceinline__ int mod96(int x) {
  int t = x >> 5;
  int q = (t * 43691) >> 17;  // floor(t/3), exact for t < 32768
  int m3 = t - q * 3;
  return (x & 31) + (m3 << 5);
}
static __device__ __forceinline__ int clampS(int x) {
  return x < 0 ? 0 : (x > S_ - 1 ? S_ - 1 : x);
}
// async global->LDS, 16B per lane; lds dest must be wave-uniform base (+lane*16)
typedef __attribute__((address_space(3))) unsigned int lds_u32_t;
typedef __attribute__((address_space(1))) const unsigned int glb_u32_t;
static __device__ __forceinline__ void gload_lds16(const void* g, void* l) {
  __builtin_amdgcn_global_load_lds((glb_u32_t*)g, (lds_u32_t*)l, 16, 0, 0);
}

// ---------------- fused prep: ln | cast | pe | wtrans x5 ----------------
// grid 1D: [0,8192) ln rows; [8192,16384) cast; [16384,20480) pe; [20480,21760) wtrans
__global__ __launch_bounds__(256) void prep_kernel(
    const float* __restrict__ inputs, const float* __restrict__ gamma,
    const float* __restrict__ beta, unsigned short* __restrict__ xb,
    const float* __restrict__ pre, unsigned short* __restrict__ preb,
    const double* __restrict__ dt, unsigned short* __restrict__ pe,
    const float* __restrict__ Wq, unsigned short* __restrict__ wtq,
    const float* __restrict__ Wk, unsigned short* __restrict__ wtk,
    const float* __restrict__ Wv, unsigned short* __restrict__ wtv,
    const float* __restrict__ Wp, unsigned short* __restrict__ wtp,
    const float* __restrict__ Wo, unsigned short* __restrict__ wto) {
  __shared__ __align__(16) float shf[64 * 65];  // wtrans tile; ln aliases head
  int bid = blockIdx.x;
  int tid = threadIdx.x;
  if (bid < 8192) {
    // ---- LayerNorm -> bf16 ----
    int row = bid;
    float4 val = ((const float4*)(inputs + (size_t)row * D_))[tid];
    float s = val.x + val.y + val.z + val.w;
    float sq = val.x * val.x + val.y * val.y + val.z * val.z + val.w * val.w;
#pragma unroll
    for (int o = 32; o > 0; o >>= 1) {
      s += __shfl_down(s, o);
      sq += __shfl_down(sq, o);
    }
    int wid = tid >> 6;
    if ((tid & 63) == 0) { shf[wid] = s; shf[4 + wid] = sq; }
    __syncthreads();
    if (tid == 0) {
      float ts = shf[0] + shf[1] + shf[2] + shf[3];
      float tq = shf[4] + shf[5] + shf[6] + shf[7];
      float mu = ts * (1.0f / D_);
      float var = tq * (1.0f / D_) - mu * mu;
      shf[8] = mu;
      shf[9] = rsqrtf(var + 1e-5f);
    }
    __syncthreads();
    float mu = shf[8], rs = shf[9];
    float4 g = ((const float4*)gamma)[tid];
    float4 be = ((const float4*)beta)[tid];
    ushort4 o;
    o.x = f2b((val.x - mu) * rs * g.x + be.x);
    o.y = f2b((val.y - mu) * rs * g.y + be.y);
    o.z = f2b((val.z - mu) * rs * g.z + be.z);
    o.w = f2b((val.w - mu) * rs * g.w + be.w);
    *(ushort4*)(xb + (size_t)row * D_ + tid * 4) = o;
    return;
  }
  bid -= 8192;
  if (bid < 8192) {
    // ---- fp32 -> bf16 cast ----
    size_t idx = (size_t)(bid * 256 + tid) * 4;
    float4 v = *(const float4*)(pre + idx);
    ushort4 o; o.x = f2b(v.x); o.y = f2b(v.y); o.z = f2b(v.z); o.w = f2b(v.w);
    *(ushort4*)(preb + idx) = o;
    return;
  }
  bid -= 8192;
  if (bid < 4096) {
    // ---- sinusoidal PE -> bf16 (f64 table angle + f32 sincos) ----
    int idx = bid * 256 + tid;  // [0, S*D/2)
    int t = idx >> 9;
    int i = idx & 511;
    double ang = (double)t * dt[i];
    double k = floor(ang * 0.15915494309189535);
    float red = (float)(ang - k * 6.283185307179586);
    ushort2 sc;
    sc.x = f2b(sinf(red));
    sc.y = f2b(cosf(red));
    *(ushort2*)(pe + (size_t)t * D_ + 2 * i) = sc;
    return;
  }
  bid -= 4096;
  // ---- W[K,N] fp32 -> WT[N,K] bf16 (64x64 tiles) ----
  const float* W; unsigned short* WT;
  switch (bid >> 8) {
    case 0: W = Wq; WT = wtq; break;
    case 1: W = Wk; WT = wtk; break;
    case 2: W = Wv; WT = wtv; break;
    case 3: W = Wp; WT = wtp; break;
    default: W = Wo; WT = wto; break;
  }
  int tile = bid & 255;
  int n0 = (tile & 15) * 64, k0 = (tile >> 4) * 64;
#pragma unroll
  for (int c = 0; c < 4; c++) {
    int idx = tid + c * 256;
    int r = idx >> 4;
    int ch = (idx & 15) * 4;
    float4 d = *(const float4*)(W + (size_t)(k0 + r) * D_ + n0 + ch);
    shf[r * 65 + ch] = d.x; shf[r * 65 + ch + 1] = d.y;
    shf[r * 65 + ch + 2] = d.z; shf[r * 65 + ch + 3] = d.w;
  }
  __syncthreads();
  {
    int n = tid >> 2;
    int ch = (tid & 3) * 16;
    unsigned short tmp[8];
#pragma unroll
    for (int half = 0; half < 2; half++) {
#pragma unroll
      for (int e = 0; e < 8; e++) tmp[e] = f2b(shf[(ch + half * 8 + e) * 65 + n]);
      *(short8*)(WT + (size_t)(n0 + n) * D_ + k0 + ch + half * 8) = *(short8*)tmp;
    }
  }
}

// ---------------- bf16 MFMA GEMM: C[M,N] = A[M,K] @ BT[N,K]^T + bias (f32 out) ----------------
__global__ __launch_bounds__(256) void gemm_out_f32(const unsigned short* __restrict__ A,
                                                    const unsigned short* __restrict__ BT,
                                                    const float* __restrict__ bias,
                                                    float* __restrict__ C,
                                                    int N) {
  const int K = D_;
  __shared__ __align__(16) unsigned short As[128 * 32];
  __shared__ __align__(16) unsigned short Bs[128 * 32];
  const int tid = threadIdx.x;
  const int wid = tid >> 6, lane = tid & 63, quad = lane >> 4, l15 = lane & 15;
  const int m0 = blockIdx.y * 128, n0 = blockIdx.x * 128;
  const int moff = (wid >> 1) * 64, noff = (wid & 1) * 64;
  f32x4 acc[4][4];
#pragma unroll
  for (int i = 0; i < 4; i++)
#pragma unroll
    for (int j = 0; j < 4; j++) acc[i][j] = (f32x4){0.f, 0.f, 0.f, 0.f};

  const int cb0 = wid * 64;
  const int c0 = cb0 + lane;
  const int r0 = c0 >> 2, ch0 = (c0 & 3) * 8;
  const int c1 = c0 + 256;
  const int r1 = c1 >> 2, ch1 = (c1 & 3) * 8;

  for (int k0 = 0; k0 < K; k0 += 32) {
    __syncthreads();
    gload_lds16(A + (size_t)(m0 + r0) * K + k0 + ch0, &As[cb0 * 8]);
    gload_lds16(BT + (size_t)(n0 + r0) * K + k0 + ch0, &Bs[cb0 * 8]);
    gload_lds16(A + (size_t)(m0 + r1) * K + k0 + ch1, &As[(cb0 + 256) * 8]);
    gload_lds16(BT + (size_t)(n0 + r1) * K + k0 + ch1, &Bs[(cb0 + 256) * 8]);
    __syncthreads();
    short8 af[4], bf[4];
#pragma unroll
    for (int i = 0; i < 4; i++)
      af[i] = *(const short8*)&As[(moff + i * 16 + l15) * 32 + quad * 8];
#pragma unroll
    for (int j = 0; j < 4; j++)
      bf[j] = *(const short8*)&Bs[(noff + j * 16 + l15) * 32 + quad * 8];
#pragma unroll
    for (int i = 0; i < 4; i++)
#pragma unroll
      for (int j = 0; j < 4; j++) acc[i][j] = MFMA_BF16(af[i], bf[j], acc[i][j]);
  }
#pragma unroll
  for (int i = 0; i < 4; i++) {
    int row = m0 + moff + i * 16 + quad * 4;
#pragma unroll
    for (int j = 0; j < 4; j++) {
      int col = n0 + noff + j * 16 + l15;
      float bb = bias[col];
#pragma unroll
      for (int g = 0; g < 4; g++)
        C[(size_t)(row + g) * N + col] = acc[i][j][g] + bb;
    }
  }
}

// ---------------- fused QK+V+P GEMM, one dispatch ----------------
// blocks [0,1024): QK (A=xb, BT=wtqk 2048 rows, dual bf16 out + bias)
// [1024,1536): V (A=preb, BT=wtv, bias bv, output TRANSPOSED to vtb[b,h,dh,s])
// [1536,1664): P (A=peb, BT=wtp, no bias, bf16 out)
__global__ __launch_bounds__(256) void gemm_fused(
    const unsigned short* __restrict__ xb, const unsigned short* __restrict__ preb,
    const unsigned short* __restrict__ peb, const unsigned short* __restrict__ wtqk,
    const unsigned short* __restrict__ wtv, const unsigned short* __restrict__ wtp,
    const float* __restrict__ bq, const float* __restrict__ bk,
    const float* __restrict__ bv, unsigned short* __restrict__ outQ,
    unsigned short* __restrict__ outK, unsigned short* __restrict__ vtb,
    unsigned short* __restrict__ outP) {
  const int K = D_;
  __shared__ __align__(16) unsigned short As[128 * 32];
  __shared__ __align__(16) unsigned short Bs[128 * 32];
  int bid = blockIdx.x;
  const unsigned short *A, *BT;
  int m0, n0, mode;
  if (bid < 1024) {
    mode = 0; A = xb; BT = wtqk;
    n0 = (bid & 15) * 128; m0 = (bid >> 4) * 128;
  } else if (bid < 1536) {
    int i = bid - 1024; mode = 1; A = preb; BT = wtv;
    n0 = (i & 7) * 128; m0 = (i >> 3) * 128;
  } else {
    int i = bid - 1536; mode = 2; A = peb; BT = wtp;
    n0 = (i & 7) * 128; m0 = (i >> 3) * 128;
  }
  const int tid = threadIdx.x;
  const int wid = tid >> 6, lane = tid & 63, quad = lane >> 4, l15 = lane & 15;
  const int moff = (wid >> 1) * 64, noff = (wid & 1) * 64;
  f32x4 acc[4][4];
#pragma unroll
  for (int i = 0; i < 4; i++)
#pragma unroll
    for (int j = 0; j < 4; j++) acc[i][j] = (f32x4){0.f, 0.f, 0.f, 0.f};

  const int cb0 = wid * 64;
  const int c0 = cb0 + lane;
  const int r0 = c0 >> 2, ch0 = (c0 & 3) * 8;
  const int c1 = c0 + 256;
  const int r1 = c1 >> 2, ch1 = (c1 & 3) * 8;

  for (int k0 = 0; k0 < K; k0 += 32) {
    __syncthreads();
    gload_lds16(A + (size_t)(m0 + r0) * K + k0 + ch0, &As[cb0 * 8]);
    gload_lds16(BT + (size_t)(n0 + r0) * K + k0 + ch0, &Bs[cb0 * 8]);
    gload_lds16(A + (size_t)(m0 + r1) * K + k0 + ch1, &As[(cb0 + 256) * 8]);
    gload_lds16(BT + (size_t)(n0 + r1) * K + k0 + ch1, &Bs[(cb0 + 256) * 8]);
    __syncthreads();
    short8 af[4], bf[4];
#pragma unroll
    for (int i = 0; i < 4; i++)
      af[i] = *(const short8*)&As[(moff + i * 16 + l15) * 32 + quad * 8];
#pragma unroll
    for (int j = 0; j < 4; j++)
      bf[j] = *(const short8*)&Bs[(noff + j * 16 + l15) * 32 + quad * 8];
#pragma unroll
    for (int i = 0; i < 4; i++)
#pragma unroll
      for (int j = 0; j < 4; j++) acc[i][j] = MFMA_BF16(af[i], bf[j], acc[i][j]);
  }

  if (mode == 0) {
    const float* bias = (n0 < D_) ? bq : bk;
    unsigned short* outp = (n0 < D_) ? outQ : outK;
    const int nn0 = n0 & (D_ - 1);
#pragma unroll
    for (int i = 0; i < 4; i++) {
      int row = m0 + moff + i * 16 + quad * 4;
#pragma unroll
      for (int j = 0; j < 4; j++) {
        int col = nn0 + noff + j * 16 + l15;
        float bb = bias[col];
#pragma unroll
        for (int g = 0; g < 4; g++)
          outp[(size_t)(row + g) * D_ + col] = f2b(acc[i][j][g] + bb);
      }
    }
  } else if (mode == 1) {
    // transposed V output: vtb[(b*16+h)*64+dh][s] = acc; row=b*S+s, col=h*64+dh
#pragma unroll
    for (int i = 0; i < 4; i++) {
      int row = m0 + moff + i * 16 + quad * 4;
      int bb_ = row >> 11, s = row & (S_ - 1);
#pragma unroll
      for (int j = 0; j < 4; j++) {
        int col = n0 + noff + j * 16 + l15;
        float bias = bv[col];
        ushort4 o;
        o.x = f2b(acc[i][j][0] + bias);
        o.y = f2b(acc[i][j][1] + bias);
        o.z = f2b(acc[i][j][2] + bias);
        o.w = f2b(acc[i][j][3] + bias);
        *(ushort4*)(vtb + ((size_t)(bb_ * 1024 + col)) * S_ + s) = o;
      }
    }
  } else {
#pragma unroll
    for (int i = 0; i < 4; i++) {
      int row = m0 + moff + i * 16 + quad * 4;
#pragma unroll
      for (int j = 0; j < 4; j++) {
        int col = n0 + noff + j * 16 + l15;
#pragma unroll
        for (int g = 0; g < 4; g++)
          outP[(size_t)(row + g) * D_ + col] = f2b(acc[i][j][g]);
      }
    }
  }
}

// ---------------- MFMA flash attention with rel-shift (transposed score) -------
// R9: SINGLE barrier per jt (was 2). ks/ps double-buffered; vts single-buffered:
// V(jt) gloaded at jt-top (oldest of exactly 3 outstanding gloads) and guarded
// by counted `s_waitcnt vmcnt(2)` before PV (T4 pattern) -- K/p prefetches stay
// in flight until the end-barrier drain, which comes a full loop body after
// their issue (cheap). K/p staged unconditionally (clamped idx) to keep the
// outstanding count exactly 3.
__global__ __launch_bounds__(256) void attn_kernel(const unsigned short* __restrict__ q,
                                                   const unsigned short* __restrict__ kg,
                                                   const unsigned short* __restrict__ vtg,
                                                   const unsigned short* __restrict__ pg,
                                                   const float* __restrict__ ub,
                                                   const float* __restrict__ vbias,
                                                   unsigned short* __restrict__ ctx) {
  // XCD-bijective swizzle (nwg = 2048 = 8*256)
  int flat = blockIdx.x + 32 * (blockIdx.y + 16 * blockIdx.z);
  int swz = (flat & 7) * 256 + (flat >> 3);
  const int i0 = (swz & 31) * 64;
  const int h = (swz >> 5) & 15;
  const int b = swz >> 9;
  const int tid = threadIdx.x;
  const int wid = tid >> 6, lane = tid & 63, quad = lane >> 4, l15 = lane & 15;
  const int wr0 = wid * 16;
  const int ib = i0 >> 5;  // first mixed jt

  __shared__ __align__(16) unsigned short ks[2][32 * 64];   // K tiles dbuf, swizzled chunks
  __shared__ __align__(16) unsigned short ps[2][32 * 64];   // p rows dbuf, swizzled
  __shared__ __align__(16) unsigned short vts[64 * 32];     // V^T single buf, linear
  __shared__ __align__(16) unsigned short prb[64 * 40];     // probs [i][j] (wave-local rows)
  __shared__ __align__(16) unsigned short bandA[64 * 100];  // ring, col mod96(r+1) (wave-local rows)
  __shared__ __align__(16) unsigned short bandB[64 * 100];  // ring, col mod96(r+2)

  const int srow = tid >> 3;                     // K/p staging row 0..31
  const int lcS = ((tid & 7) ^ (srow & 7)) * 8;  // swizzled logical chunk (u16 off)
  const int vrow = tid >> 2, vch = (tid & 3) * 8;  // V staging (linear)
  const int pc0 = (quad ^ (l15 & 7)) * 8;        // read-side physical chunk (u16 off)

  // global bases
  const unsigned short* kgl = kg + ((size_t)b * S_ * H_ + h) * DH_ + lcS;  // + j*H_*DH_
  const unsigned short* pgl = pg + h * 64 + lcS;                           // + rc*D_
  const unsigned short* vgl = vtg + ((size_t)(b * H_ + h) * 64 + vrow) * S_ + vch;  // + j
  // LDS wave-uniform staging bases (u16 index)
  const int wb = wid * 512;  // 64 chunks * 8 u16

  // ---- direct q fragment loads: (q+u) for content, (q+v) for bands ----
  short8 qc0, qc1, qA0, qA1, qB0, qB1;
  {
    auto ldq2 = [&](int r, int c0, short8& outU, short8& outV) {
      int qi = i0 + r; if (qi > S_ - 1) qi = S_ - 1;
      short8 raw = *(const short8*)(q + (((size_t)b * S_ + qi) * H_ + h) * DH_ + c0);
      unsigned short tu[8], tv[8];
#pragma unroll
      for (int e = 0; e < 8; e++) {
        float f = b2f((unsigned short)raw[e]);
        tu[e] = f2b(f + ub[h * 64 + c0 + e]);
        tv[e] = f2b(f + vbias[h * 64 + c0 + e]);
      }
      outU = *(short8*)tu;
      outV = *(short8*)tv;
    };
    auto ldqv = [&](int r, int c0) -> short8 {
      int qi = i0 + r; if (qi > S_ - 1) qi = S_ - 1;
      short8 raw = *(const short8*)(q + (((size_t)b * S_ + qi) * H_ + h) * DH_ + c0);
      unsigned short tv[8];
#pragma unroll
      for (int e = 0; e < 8; e++)
        tv[e] = f2b(b2f((unsigned short)raw[e]) + vbias[h * 64 + c0 + e]);
      return *(short8*)tv;
    };
    ldq2(wr0 + l15, quad * 8, qc0, qA0);
    ldq2(wr0 + l15, 32 + quad * 8, qc1, qA1);
    qB0 = ldqv(wr0 + l15 + 1, quad * 8);
    qB1 = ldqv(wr0 + l15 + 1, 32 + quad * 8);
  }

  const int brow = (wr0 + l15) * 100;  // own band row (write AND read)

  // band MFMA, swapped operands; src = ps buffer (pitch 64, swizzled chunks)
  auto band_compute = [&](const unsigned short* src, int w, int rhi) {
    int rbase = rhi - 31;
    short8 a0 = w ? qB0 : qA0;
    short8 a1 = w ? qB1 : qA1;
    unsigned short* band = w ? bandB : bandA;
    const int OFF = w ? 2 : 1;
#pragma unroll
    for (int ct = 0; ct < 2; ct++) {
      int ro = (ct * 16 + l15) * 64;
      short8 b0 = *(const short8*)&src[ro + pc0];
      short8 b1 = *(const short8*)&src[ro + (pc0 ^ 32)];
      f32x4 acc = (f32x4){0.f, 0.f, 0.f, 0.f};
      acc = MFMA_BF16(b0, a0, acc);   // A = p rows, B = (q+v) rows
      acc = MFMA_BF16(b1, a1, acc);
      int r0 = rbase + ct * 16 + quad * 4;
      int col = mod96(r0 + 960 + OFF);   // === 0 mod 4 -> b64 aligned
      uint2 pv = make_uint2(pk2(acc[0], acc[1]), pk2(acc[2], acc[3]));
      *(uint2*)&band[brow + col] = pv;
      if (col == 0) *(uint2*)&band[brow + 96] = pv;  // mirror guard 96..99
    }
  };

  // ---- prologue: stage K(0) + 5 band backfill tasks via gload ----
  {
    const int TW[5] = {0, 0, 0, 1, 1};
    const int TR[5] = {S_ + 30 - i0 - 64, S_ + 30 - i0 - 32, S_ + 30 - i0, 29, 61};
    {
      int rc = clampS(TR[0] - 31 + srow);
      gload_lds16(pgl + (size_t)rc * D_, &ps[0][wb]);
      gload_lds16(kgl + (size_t)srow * (H_ * DH_), &ks[0][wb]);
    }
    __syncthreads();
#pragma unroll
    for (int t = 0; t < 5; t++) {
      if (t < 4) {
        int rc = clampS(TR[t + 1] - 31 + srow);
        gload_lds16(pgl + (size_t)rc * D_, &ps[(t + 1) & 1][wb]);
      }
      band_compute(ps[t & 1], TW[t], TR[t]);
      __syncthreads();
    }
  }

  float lsum = 0.f;  // per thread: i = i0 + wr0 + l15 fixed
  f32x4 Oa[4];
#pragma unroll
  for (int ct = 0; ct < 4; ct++) Oa[ct] = (f32x4){0.f, 0.f, 0.f, 0.f};

  // ring cols for (g=0, ct=0), advance +32 mod 96 / jt; include OFF rotation
  int cA = mod96(S_ + quad * 4 - i0 - wr0 - l15);          // OFF_A=1 folded in
  int cB = mod96(2112 + quad * 4 - i0 - wr0 - l15);        // OFF_B=2 folded in
  int cwin = 0, crhi = 0, chave = 0;

  const float SCL = 0.03125f;
  const unsigned int prbw = (wr0 + l15) * 40 + quad * 4;

  for (int jt = 0; jt < 64; jt++) {
    const int j0 = jt * 32;
    const int cur = jt & 1, nxt = cur ^ 1;
    // ---- issue async stages: V(jt)->vts (FIRST, oldest), K(jt+1)->ks[nxt],
    //      p(task jt+1)->ps[nxt]. Always exactly 3 outstanding after this.
    int nwin, nrhi;
    {
      gload_lds16(vgl + (size_t)j0, &vts[wb]);
      int j0n = (jt < 63) ? j0 + 32 : j0;  // clamped (jt=63 garbage, never read)
      gload_lds16(kgl + (size_t)(j0n + srow) * (H_ * DH_), &ks[nxt][wb]);
      int j0x = j0 + 32;
      if (j0x <= i0 + 63) { nwin = 0; nrhi = S_ + 30 - i0 + j0x; }
      else                { nwin = 1; nrhi = j0x - i0 + 29; }
      int rc = clampS(nrhi - 31 + srow);
      gload_lds16(pgl + (size_t)rc * D_, &ps[nxt][wb]);
    }
    __builtin_amdgcn_s_setprio(1);
    // ---- band MFMA for task(jt), staged at jt-1 ----
    if (chave) band_compute(ps[cur], cwin, crhi);
    // ---- content MFMA, transposed: Sc^T rows=j, cols=i (ks swizzled reads) ----
    f32x4 cc[2];
    {
#pragma unroll
      for (int ct = 0; ct < 2; ct++) {
        int ro = (ct * 16 + l15) * 64;
        short8 a0 = *(const short8*)&ks[cur][ro + pc0];
        short8 a1 = *(const short8*)&ks[cur][ro + (pc0 ^ 32)];
        f32x4 acc = (f32x4){0.f, 0.f, 0.f, 0.f};
        acc = MFMA_BF16(a0, qc0, acc);
        acc = MFMA_BF16(a1, qc1, acc);
        cc[ct] = acc;
      }
    }
    __builtin_amdgcn_s_setprio(0);
    // ---- score: thread = (i fixed, j = j0 + ct*16 + quad*4 + g) ----
    if (jt < ib) {
#pragma unroll
      for (int ct = 0; ct < 2; ct++) {
        int c0 = ct ? (cA + 16 >= 96 ? cA + 16 - 96 : cA + 16) : cA;
        const unsigned short* base = &bandA[brow + c0];
        float e0 = __expf((cc[ct][0] + b2f(base[0])) * SCL);
        float e1 = __expf((cc[ct][1] + b2f(base[1])) * SCL);
        float e2 = __expf((cc[ct][2] + b2f(base[2])) * SCL);
        float e3 = __expf((cc[ct][3] + b2f(base[3])) * SCL);
        *(uint2*)&prb[prbw + ct * 16] = make_uint2(pk2(e0, e1), pk2(e2, e3));
        lsum += (e0 + e1) + (e2 + e3);
      }
    } else if (jt >= ib + 3) {
#pragma unroll
      for (int ct = 0; ct < 2; ct++) {
        int c0 = ct ? (cB + 16 >= 96 ? cB + 16 - 96 : cB + 16) : cB;
        const unsigned short* base = &bandB[brow + c0];
        float e0 = __expf((cc[ct][0] + b2f(base[0])) * SCL);
        float e1 = __expf((cc[ct][1] + b2f(base[1])) * SCL);
        float e2 = __expf((cc[ct][2] + b2f(base[2])) * SCL);
        float e3 = __expf((cc[ct][3] + b2f(base[3])) * SCL);
        *(uint2*)&prb[prbw + ct * 16] = make_uint2(pk2(e0, e1), pk2(e2, e3));
        lsum += (e0 + e1) + (e2 + e3);
      }
    } else {
      // mixed: generic per element; OFF rotation applied (A:+1, B:+2)
#pragma unroll
      for (int ct = 0; ct < 2; ct++) {
        int jbase = j0 + ct * 16 + quad * 4;
        float ev[4];
#pragma unroll
        for (int g = 0; g < 4; g++) {
          int d = jbase + g - (i0 + wr0 + l15);
          float t;
          if (d == 1) t = 0.f;
          else if (d <= 0) t = b2f(bandA[brow + mod96(S_ + d)]);      // r=S-1+d, +1
          else t = b2f(bandB[brow + mod96(d)]);                        // r=d-2, +2
          ev[g] = __expf((cc[ct][g] + t) * SCL);
          lsum += ev[g];
        }
        *(uint2*)&prb[prbw + ct * 16] = make_uint2(pk2(ev[0], ev[1]), pk2(ev[2], ev[3]));
      }
    }
    // ---- wait V(jt) landed: 3 outstanding, V oldest -> vmcnt(2) ----
    asm volatile("s_waitcnt vmcnt(2)" ::: "memory");
    // ---- PV MFMA: O[i 16][dh 64] += P(16x32) @ V(32x64) ----
    {
      short8 af = *(const short8*)&prb[(wr0 + l15) * 40 + quad * 8];
#pragma unroll
      for (int ct = 0; ct < 4; ct++) {
        short8 bf = *(const short8*)&vts[(ct * 16 + l15) * 32 + quad * 8];
        Oa[ct] = MFMA_BF16(af, bf, Oa[ct]);
      }
    }
    __syncthreads();  // single barrier: drains K/p gloads + swaps buffers
    cwin = nwin; crhi = nrhi; chave = 1;
    cA += 32; if (cA >= 96) cA -= 96;
    cB += 32; if (cB >= 96) cB -= 96;
  }
  // ---- epilogue ----
  float ltot = lsum;
  ltot += __shfl_xor(ltot, 16);
  ltot += __shfl_xor(ltot, 32);
#pragma unroll
  for (int g = 0; g < 4; g++) {
    float lg = __shfl(ltot, quad * 4 + g);
    float inv = 1.f / lg;
    int i = i0 + wr0 + quad * 4 + g;
    unsigned short* dst = ctx + ((size_t)b * S_ + i) * D_ + h * 64;
#pragma unroll
    for (int ct = 0; ct < 4; ct++) dst[ct * 16 + l15] = f2b(Oa[ct][g] * inv);
  }
}

extern "C" void kernel_launch(void* const* d_in, const int* in_sizes, int n_in,
                              void* d_out, int out_size, void* d_ws, size_t ws_size,
                              hipStream_t stream) {
  const float* inputs = (const float*)d_in[0];
  const float* pre_block = (const float*)d_in[1];
  const float* ln_gamma = (const float*)d_in[2];
  const float* ln_beta = (const float*)d_in[3];
  const float* Wq = (const float*)d_in[4];
  const float* bq = (const float*)d_in[5];
  const float* Wk = (const float*)d_in[6];
  const float* bk = (const float*)d_in[7];
  const float* Wv = (const float*)d_in[8];
  const float* bv = (const float*)d_in[9];
  const float* Wpos = (const float*)d_in[10];
  const float* u_bias = (const float*)d_in[11];
  const float* v_bias = (const float*)d_in[12];
  const float* Wo = (const float*)d_in[13];
  const float* bo = (const float*)d_in[14];
  float* out = (float*)d_out;

  char* ws = (char*)d_ws;
  const size_t NBS = (size_t)B_ * S_ * D_;  // 8388608
  unsigned short* xb = (unsigned short*)ws;
  unsigned short* ctx = (unsigned short*)ws;               // alias (xb dead after qk-GEMM)
  unsigned short* preb = (unsigned short*)(ws + NBS * 2);
  unsigned short* peb = (unsigned short*)(ws + NBS * 4);
  char* base = ws + NBS * 4 + (size_t)S_ * D_ * 2;
  unsigned short* wtq = (unsigned short*)(base);           // wtq||wtk contiguous (fused QK)
  unsigned short* wtk = (unsigned short*)(base + (size_t)D_ * D_ * 2);
  unsigned short* wtv = (unsigned short*)(base + (size_t)D_ * D_ * 4);
  unsigned short* wtp = (unsigned short*)(base + (size_t)D_ * D_ * 6);
  unsigned short* wto = (unsigned short*)(base + (size_t)D_ * D_ * 8);
  unsigned short* qb = (unsigned short*)(base + (size_t)D_ * D_ * 10);
  unsigned short* kb = qb + NBS;
  unsigned short* vtb = kb + NBS;          // V written transposed directly by gemm_fused
  unsigned short* pb = vtb + NBS;
  double* divtab = (double*)(pb + (size_t)S_ * D_);  // dedicated 4KB slot

  // host-computed f64 div table (512 exps once; async H2D, graph-capture safe)
  static double h_divtab[512];
  static bool h_init = false;
  if (!h_init) {
    for (int i = 0; i < 512; i++)
      h_divtab[i] = exp(-(log(10000.0) * (2.0 * i) / (double)D_));
    h_init = true;
  }
  hipMemcpyAsync(divtab, h_divtab, 512 * sizeof(double), hipMemcpyHostToDevice, stream);

  prep_kernel<<<21760, 256, 0, stream>>>(inputs, ln_gamma, ln_beta, xb,
                                         pre_block, preb, divtab, peb,
                                         Wq, wtq, Wk, wtk, Wv, wtv, Wpos, wtp, Wo, wto);
  gemm_fused<<<1664, 256, 0, stream>>>(xb, preb, peb, wtq, wtv, wtp,
                                       bq, bk, bv, qb, kb, vtb, pb);
  attn_kernel<<<dim3(32, 16, 4), 256, 0, stream>>>(qb, kb, vtb, pb, u_bias, v_bias, ctx);
  gemm_out_f32<<<dim3(8, 64), 256, 0, stream>>>(ctx, wto, bo, out, D_);
}